// Round 17
// baseline (637.447 us; speedup 1.0000x reference)
//
#include <hip/hip_runtime.h>
#include <math.h>

// Problem constants (match reference)
#define NNODES 50000
#define NEDGES 800000
#define ETOT   (NNODES + NEDGES)   // 850000 edges incl. self-loops
#define EDIM   10
#define SMEPS  1e-16f
#define BNEPS  1e-5f
#define NSLOPE 0.2f

#define SCANB  ((NNODES + 255) / 256)   // 196 scan blocks
#define EASUMB 256                      // easum partial blocks
#define BNB    256                      // bnstats partial blocks
#define CPAD   32                       // ints per 128B line: 1 counter/line

typedef _Float16 f16;
typedef f16 f16x8 __attribute__((ext_vector_type(8)));
typedef f16 f16x4 __attribute__((ext_vector_type(4)));
typedef float f32x4 __attribute__((ext_vector_type(4)));

// ---------------------------------------------------------------------------
// Graph preprocessing: CSR by destination (built once per call, reused 3x)
// deg/cursor are PADDED to one counter per 128B cache line: a dense layout
// packs 32 counters/line -> ~544 atomics serializing per line across XCDs
// (measured: k_scatter 60us at 13% HBM). Padding cuts contention 32x.
// ---------------------------------------------------------------------------

__global__ void k_deg(const int* __restrict__ edst, int* __restrict__ deg) {
    int e = blockIdx.x * blockDim.x + threadIdx.x;
    if (e >= ETOT) return;
    int d = (e < NEDGES) ? edst[e] : (e - NEDGES);   // self-loop dst = node id
    atomicAdd(&deg[(long)d * CPAD], 1);
}

// edge_attr column sums -> per-block partials (NO global float atomics)
__global__ void k_easum(const float* __restrict__ ea, float* __restrict__ part) {
    float acc[EDIM];
#pragma unroll
    for (int d = 0; d < EDIM; ++d) acc[d] = 0.f;
    int tid = blockIdx.x * blockDim.x + threadIdx.x;
    const int np = NEDGES / 2;   // 400000 pairs (NEDGES even)
    for (int p = tid; p < np; p += gridDim.x * blockDim.x) {
        const float4* q = (const float4*)&ea[(long)p * 20];
        float4 v0 = q[0], v1 = q[1], v2 = q[2], v3 = q[3], v4 = q[4];
        acc[0] += v0.x + v2.z;
        acc[1] += v0.y + v2.w;
        acc[2] += v0.z + v3.x;
        acc[3] += v0.w + v3.y;
        acc[4] += v1.x + v3.z;
        acc[5] += v1.y + v3.w;
        acc[6] += v1.z + v4.x;
        acc[7] += v1.w + v4.y;
        acc[8] += v2.x + v4.z;
        acc[9] += v2.y + v4.w;
    }
    __shared__ float sm[256];
    for (int d = 0; d < EDIM; ++d) {
        sm[threadIdx.x] = acc[d];
        __syncthreads();
        for (int s = 128; s > 0; s >>= 1) {
            if (threadIdx.x < s) sm[threadIdx.x] += sm[threadIdx.x + s];
            __syncthreads();
        }
        if (threadIdx.x == 0) part[blockIdx.x * EDIM + d] = sm[0];
        __syncthreads();
    }
}

// Hierarchical exclusive scan (multi-block). Reads the PADDED deg array
// (strided 128B: ~6.4MB of line traffic, ~1us — negligible).
__global__ void k_scan1(const int* __restrict__ deg, int* __restrict__ off,
                        int* __restrict__ partials) {
    __shared__ int sm[256];
    int t = threadIdx.x;
    int i = blockIdx.x * 256 + t;
    int v = (i < NNODES) ? deg[(long)i * CPAD] : 0;
    sm[t] = v;
    __syncthreads();
    int val = v;
    for (int d = 1; d < 256; d <<= 1) {
        int tv = (t >= d) ? sm[t - d] : 0;
        __syncthreads();
        val += tv;
        sm[t] = val;
        __syncthreads();
    }
    if (i < NNODES) off[i] = val - v;          // exclusive within block
    if (t == 255) partials[blockIdx.x] = val;  // block total
}

__global__ void k_scan2(int* __restrict__ partials, int* __restrict__ off) {
    __shared__ int sm[256];
    int t = threadIdx.x;
    int v = (t < SCANB) ? partials[t] : 0;
    sm[t] = v;
    __syncthreads();
    int val = v;
    for (int d = 1; d < 256; d <<= 1) {
        int tv = (t >= d) ? sm[t - d] : 0;
        __syncthreads();
        val += tv;
        sm[t] = val;
        __syncthreads();
    }
    if (t < SCANB) partials[t] = val - v;      // exclusive block offset
    if (t == 255) off[NNODES] = ETOT;          // total is a known constant
}

__global__ void k_scan3(int* __restrict__ off, const int* __restrict__ partials) {
    int i = blockIdx.x * 256 + threadIdx.x;
    if (i < NNODES) off[i] += partials[blockIdx.x];
}

__global__ void k_scatter(const int* __restrict__ esrc, const int* __restrict__ edst,
                          const int* __restrict__ off, int* __restrict__ cursor,
                          int* __restrict__ csr_src, int* __restrict__ perm) {
    int e = blockIdx.x * blockDim.x + threadIdx.x;
    if (e >= ETOT) return;
    int s, d;
    if (e < NEDGES) { s = esrc[e]; d = edst[e]; }
    else            { s = d = e - NEDGES; }
    int pos  = atomicAdd(&cursor[(long)d * CPAD], 1);
    int slot = off[d] + pos;
    csr_src[slot] = s;
    perm[e] = slot;
}

// h0 = concat(x[N,40], cdk[N,200]) -> fp16 [N,256], cols 240..255 zero-padded
__global__ void k_concat_h(const float* __restrict__ x, const float* __restrict__ cdk,
                           f16* __restrict__ out) {
    int i = blockIdx.x * blockDim.x + threadIdx.x;
    if (i >= NNODES * 256) return;
    int n = i >> 8, j = i & 255;
    float v = (j < 40) ? x[n * 40 + j] : (j < 240) ? cdk[n * 200 + (j - 40)] : 0.f;
    out[i] = (f16)v;
}

// All three weight transposes in one launch: Wt[n][k] = fp16(W[k][n]), k padded
__global__ void k_wcvt_all(const float* __restrict__ W0, const float* __restrict__ W1,
                           const float* __restrict__ W2, f16* __restrict__ Wt0,
                           f16* __restrict__ Wt1, f16* __restrict__ Wt2) {
    int i = blockIdx.x * blockDim.x + threadIdx.x;
    const float* W; f16* Wt; int K, NC, j;
    if (i < 65536)       { W = W0; Wt = Wt0; K = 240; NC = 256; j = i; }
    else if (i < 131072) { W = W1; Wt = Wt1; K = 256; NC = 256; j = i - 65536; }
    else if (i < 147456) { W = W2; Wt = Wt2; K = 256; NC = 64;  j = i - 131072; }
    else return;
    int n = j >> 8, k = j & 255;
    Wt[j] = (k < K) ? (f16)W[k * NC + n] : (f16)0.f;
}

// ---------------------------------------------------------------------------
// fp16 MFMA GEMM + fused attention-coefficient epilogue.
// C[M,NC] = A[M,256] @ B(256,NC) with Bt[NC,256]; 128x64 tile, 4 waves.
// Each block's 64-col slice == one head (blockIdx.y), so al_s[r,h], al_d[r,h]
// are computed exactly from the fp32 accumulators: 4 FMAs + 16-lane shfl_xor
// reduce per row.
// ---------------------------------------------------------------------------
#define GM_LDS 40
__global__ __launch_bounds__(256) void k_gemm_h(const f16* __restrict__ A,
                                                const f16* __restrict__ Bt,
                                                f16* __restrict__ C,
                                                const float* __restrict__ a_s,
                                                const float* __restrict__ a_d,
                                                float* __restrict__ als,
                                                float* __restrict__ ald,
                                                int M, int NC, int H) {
    __shared__ f16 As[128 * GM_LDS];
    __shared__ f16 Bs[64 * GM_LDS];
    const int t    = threadIdx.x;
    const int w    = t >> 6;
    const int lane = t & 63;
    const int row0 = blockIdx.x * 128;
    const int col0 = blockIdx.y * 64;

    const int ar = t >> 1;              // A stage: row 0..127
    const int ak = (t & 1) * 16;        //          16-half chunk offset 0/16
    const int bn = t >> 2;              // B stage: n 0..63
    const int bk = (t & 3) * 8;         //          k-offset 0/8/16/24

    const int l16 = lane & 15;
    const int kg  = lane >> 4;

    f32x4 acc[2][4];
#pragma unroll
    for (int i = 0; i < 2; ++i)
#pragma unroll
        for (int j = 0; j < 4; ++j) acc[i][j] = {0.f, 0.f, 0.f, 0.f};

    for (int k0 = 0; k0 < 256; k0 += 32) {
        f16x8 av0, av1;
#pragma unroll
        for (int i = 0; i < 8; ++i) { av0[i] = (f16)0.f; av1[i] = (f16)0.f; }
        if (row0 + ar < M) {
            const f16* ap = &A[(long)(row0 + ar) * 256 + k0 + ak];
            av0 = *(const f16x8*)ap;
            av1 = *(const f16x8*)(ap + 8);
        }
        *(f16x8*)&As[ar * GM_LDS + ak]     = av0;
        *(f16x8*)&As[ar * GM_LDS + ak + 8] = av1;
        f16x8 bv = *(const f16x8*)&Bt[(long)(col0 + bn) * 256 + k0 + bk];
        *(f16x8*)&Bs[bn * GM_LDS + bk] = bv;
        __syncthreads();

        f16x8 afr[2], bfr[4];
#pragma unroll
        for (int mi = 0; mi < 2; ++mi)
            afr[mi] = *(const f16x8*)&As[(w * 32 + mi * 16 + l16) * GM_LDS + kg * 8];
#pragma unroll
        for (int ni = 0; ni < 4; ++ni)
            bfr[ni] = *(const f16x8*)&Bs[(ni * 16 + l16) * GM_LDS + kg * 8];
#pragma unroll
        for (int mi = 0; mi < 2; ++mi)
#pragma unroll
            for (int ni = 0; ni < 4; ++ni)
                acc[mi][ni] = __builtin_amdgcn_mfma_f32_16x16x32_f16(
                    afr[mi], bfr[ni], acc[mi][ni], 0, 0, 0);
        __syncthreads();
    }

    // C write
#pragma unroll
    for (int mi = 0; mi < 2; ++mi)
#pragma unroll
        for (int ni = 0; ni < 4; ++ni)
#pragma unroll
            for (int j = 0; j < 4; ++j) {
                int r = row0 + w * 32 + mi * 16 + kg * 4 + j;
                if (r < M) C[(long)r * NC + col0 + ni * 16 + l16] = (f16)acc[mi][ni][j];
            }

    // fused al_s/al_d: this block's 64 cols = head hidx fully
    const int hidx = blockIdx.y;
    float asv[4], adv[4];
#pragma unroll
    for (int ni = 0; ni < 4; ++ni) {
        asv[ni] = a_s[hidx * 64 + ni * 16 + l16];
        adv[ni] = a_d[hidx * 64 + ni * 16 + l16];
    }
#pragma unroll
    for (int mi = 0; mi < 2; ++mi)
#pragma unroll
        for (int j = 0; j < 4; ++j) {
            float ps = acc[mi][0][j] * asv[0] + acc[mi][1][j] * asv[1]
                     + acc[mi][2][j] * asv[2] + acc[mi][3][j] * asv[3];
            float pd = acc[mi][0][j] * adv[0] + acc[mi][1][j] * adv[1]
                     + acc[mi][2][j] * adv[2] + acc[mi][3][j] * adv[3];
#pragma unroll
            for (int o = 1; o < 16; o <<= 1) {
                ps += __shfl_xor(ps, o);
                pd += __shfl_xor(pd, o);
            }
            int r = row0 + w * 32 + mi * 16 + kg * 4 + j;
            if (l16 == 0 && r < M) {
                als[(long)r * H + hidx] = ps;
                ald[(long)r * H + hidx] = pd;
            }
        }
}

// All 3 layers' Ve[d,h] and loop_al[h] in one launch (block = layer, 1 wave).
// Also reduces the easum partials in-register (replaces the atomic easum).
__global__ void k_ve_all(const float* __restrict__ We0, const float* __restrict__ ae0,
                         const float* __restrict__ We1, const float* __restrict__ ae1,
                         const float* __restrict__ We2, const float* __restrict__ ae2,
                         const float* __restrict__ eapart,
                         float* __restrict__ VeAll, float* __restrict__ laAll) {
    int l = blockIdx.x;
    const float* We = (l == 0) ? We0 : (l == 1) ? We1 : We2;
    const float* ae = (l == 0) ? ae0 : (l == 1) ? ae1 : ae2;
    int H = (l == 2) ? 1 : 4;
    float* Ve = VeAll + l * 48;
    float* la = laAll + l * 4;
    int t = threadIdx.x;          // 0..63, one wave

    float ac[EDIM];
#pragma unroll
    for (int d = 0; d < EDIM; ++d) ac[d] = 0.f;
    for (int r = t; r < EASUMB; r += 64) {
#pragma unroll
        for (int d = 0; d < EDIM; ++d) ac[d] += eapart[r * EDIM + d];
    }
#pragma unroll
    for (int o = 1; o < 64; o <<= 1) {
#pragma unroll
        for (int d = 0; d < EDIM; ++d) ac[d] += __shfl_xor(ac[d], o);
    }

    if (t < EDIM * H) {
        int d = t / H, h = t % H;
        float s = 0.f;
        for (int c = 0; c < 64; ++c) s += We[d * (H * 64) + h * 64 + c] * ae[h * 64 + c];
        Ve[d * H + h] = s;
    }
    __syncthreads();
    if (t < H) {
        float s = 0.f;
        for (int d = 0; d < EDIM; ++d) s += (ac[d] * (1.0f / NEDGES)) * Ve[d * H + t];
        la[t] = s;
    }
}

// Edge-parallel alpha (fp16 logits), written in CSR order via perm.
template <int H>
__global__ void k_edge(const float* __restrict__ ea, const int* __restrict__ esrc,
                       const int* __restrict__ edst, const float* __restrict__ als,
                       const float* __restrict__ ald, const float* __restrict__ Ve,
                       const float* __restrict__ loop_al, const int* __restrict__ perm,
                       f16* __restrict__ alpha) {
    int e = blockIdx.x * blockDim.x + threadIdx.x;
    if (e >= ETOT) return;
    int s, d;
    float ale[H];
    if (e < NEDGES) {
        s = esrc[e]; d = edst[e];
#pragma unroll
        for (int h = 0; h < H; ++h) ale[h] = 0.f;
#pragma unroll
        for (int dd = 0; dd < EDIM; ++dd) {
            float v = ea[(long)e * EDIM + dd];
#pragma unroll
            for (int h = 0; h < H; ++h) ale[h] = fmaf(v, Ve[dd * H + h], ale[h]);
        }
    } else {
        s = d = e - NEDGES;
#pragma unroll
        for (int h = 0; h < H; ++h) ale[h] = loop_al[h];
    }
    int slot = perm[e];
#pragma unroll
    for (int h = 0; h < H; ++h) {
        float a = als[s * H + h] + ald[d * H + h] + ale[h];
        a = (a > 0.f) ? a : NSLOPE * a;
        alpha[(long)slot * H + h] = (f16)a;
    }
}

// ---------------------------------------------------------------------------
// Node-parallel softmax + aggregation, lane-distributed, fp16 row gather with
// fp32 accumulate. One wave per node; alpha AND csr_src cached in registers;
// exp weights + src indices broadcast via uniform-source __shfl; gather loop
// 4-way unrolled (4 loads in flight — the measured TLP/ILP optimum). fp16 out.
// ---------------------------------------------------------------------------
template <int H>
__global__ __launch_bounds__(256) void k_agg(const f16* __restrict__ xp,
                                             const f16* __restrict__ alpha,
                                             const int* __restrict__ off,
                                             const int* __restrict__ csr_src,
                                             f16* __restrict__ out) {
    int gw   = (blockIdx.x * blockDim.x + threadIdx.x) >> 6;
    int lane = threadIdx.x & 63;
    if (gw >= NNODES) return;
    int o0 = off[gw], o1 = off[gw + 1];

    if constexpr (H == 4) {
        constexpr int T = 4;                 // caches up to 64 edges/node
        int h  = lane >> 4;
        int il = lane & 15;
        int glane = lane & 48;               // first lane of this head's group

        // pass 1: distributed load of alpha + csr_src (register-cached)
        float av[T];
        int   idx[T];
        float mx = -INFINITY;
#pragma unroll
        for (int t = 0; t < T; ++t) {
            int s = o0 + t * 16 + il;
            bool ok = (s < o1);
            float a = ok ? (float)alpha[(long)s * 4 + h] : -INFINITY;
            idx[t] = ok ? csr_src[s] : 0;
            av[t] = a;
            mx = fmaxf(mx, a);
        }
        for (int s = o0 + T * 16 + il; s < o1; s += 16)   // rare tail
            mx = fmaxf(mx, (float)alpha[(long)s * 4 + h]);
#pragma unroll
        for (int o = 1; o < 16; o <<= 1) mx = fmaxf(mx, __shfl_xor(mx, o));

        // pass 2: exp from registers, group-reduced denominator
        float den = 0.f;
#pragma unroll
        for (int t = 0; t < T; ++t) {
            float e = expf(av[t] - mx);      // exp(-inf)=0 handles padding
            av[t] = e;
            den += e;
        }
        for (int s = o0 + T * 16 + il; s < o1; s += 16)   // rare tail
            den += expf((float)alpha[(long)s * 4 + h] - mx);
#pragma unroll
        for (int o = 1; o < 16; o <<= 1) den += __shfl_xor(den, o);
        float di = 1.0f / (den + SMEPS);

        // pass 3: weighted gather, 4-way unrolled (4 loads in flight)
        float4 acc0 = make_float4(0.f, 0.f, 0.f, 0.f);
        float4 acc1 = make_float4(0.f, 0.f, 0.f, 0.f);
#pragma unroll
        for (int t = 0; t < T; ++t) {
            int base = o0 + t * 16;
            if (base >= o1) break;
            int cnt = min(16, o1 - base);
            int j = 0;
            for (; j + 4 <= cnt; j += 4) {
                float w0 = __shfl(av[t],  glane + j,     64);
                int  sn0 = __shfl(idx[t], glane + j,     64);
                float w1 = __shfl(av[t],  glane + j + 1, 64);
                int  sn1 = __shfl(idx[t], glane + j + 1, 64);
                float w2 = __shfl(av[t],  glane + j + 2, 64);
                int  sn2 = __shfl(idx[t], glane + j + 2, 64);
                float w3 = __shfl(av[t],  glane + j + 3, 64);
                int  sn3 = __shfl(idx[t], glane + j + 3, 64);
                f16x4 x0 = *(const f16x4*)&xp[(long)sn0 * 256 + lane * 4];
                f16x4 x1 = *(const f16x4*)&xp[(long)sn1 * 256 + lane * 4];
                f16x4 x2 = *(const f16x4*)&xp[(long)sn2 * 256 + lane * 4];
                f16x4 x3 = *(const f16x4*)&xp[(long)sn3 * 256 + lane * 4];
                acc0.x = fmaf(w0, (float)x0[0], acc0.x);
                acc0.y = fmaf(w0, (float)x0[1], acc0.y);
                acc0.z = fmaf(w0, (float)x0[2], acc0.z);
                acc0.w = fmaf(w0, (float)x0[3], acc0.w);
                acc1.x = fmaf(w1, (float)x1[0], acc1.x);
                acc1.y = fmaf(w1, (float)x1[1], acc1.y);
                acc1.z = fmaf(w1, (float)x1[2], acc1.z);
                acc1.w = fmaf(w1, (float)x1[3], acc1.w);
                acc0.x = fmaf(w2, (float)x2[0], acc0.x);
                acc0.y = fmaf(w2, (float)x2[1], acc0.y);
                acc0.z = fmaf(w2, (float)x2[2], acc0.z);
                acc0.w = fmaf(w2, (float)x2[3], acc0.w);
                acc1.x = fmaf(w3, (float)x3[0], acc1.x);
                acc1.y = fmaf(w3, (float)x3[1], acc1.y);
                acc1.z = fmaf(w3, (float)x3[2], acc1.z);
                acc1.w = fmaf(w3, (float)x3[3], acc1.w);
            }
            for (; j < cnt; ++j) {
                float w  = __shfl(av[t],  glane + j, 64);
                int   sn = __shfl(idx[t], glane + j, 64);
                f16x4 xh = *(const f16x4*)&xp[(long)sn * 256 + lane * 4];
                acc0.x = fmaf(w, (float)xh[0], acc0.x);
                acc0.y = fmaf(w, (float)xh[1], acc0.y);
                acc0.z = fmaf(w, (float)xh[2], acc0.z);
                acc0.w = fmaf(w, (float)xh[3], acc0.w);
            }
        }
        for (int s = o0 + T * 16; s < o1; ++s) {          // rare tail
            float w  = expf((float)alpha[(long)s * 4 + h] - mx);
            int   sn = csr_src[s];
            f16x4 xh = *(const f16x4*)&xp[(long)sn * 256 + lane * 4];
            acc0.x = fmaf(w, (float)xh[0], acc0.x);
            acc0.y = fmaf(w, (float)xh[1], acc0.y);
            acc0.z = fmaf(w, (float)xh[2], acc0.z);
            acc0.w = fmaf(w, (float)xh[3], acc0.w);
        }
        f16x4 o4 = {(f16)((acc0.x + acc1.x) * di), (f16)((acc0.y + acc1.y) * di),
                    (f16)((acc0.z + acc1.z) * di), (f16)((acc0.w + acc1.w) * di)};
        *(f16x4*)&out[(long)gw * 256 + lane * 4] = o4;
    } else {
        constexpr int T = 2;                 // caches up to 128 edges/node
        float av[T];
        int   idx[T];
        float mx = -INFINITY;
#pragma unroll
        for (int t = 0; t < T; ++t) {
            int s = o0 + t * 64 + lane;
            bool ok = (s < o1);
            float a = ok ? (float)alpha[s] : -INFINITY;
            idx[t] = ok ? csr_src[s] : 0;
            av[t] = a;
            mx = fmaxf(mx, a);
        }
        for (int s = o0 + T * 64 + lane; s < o1; s += 64)
            mx = fmaxf(mx, (float)alpha[s]);
#pragma unroll
        for (int o = 1; o < 64; o <<= 1) mx = fmaxf(mx, __shfl_xor(mx, o));

        float den = 0.f;
#pragma unroll
        for (int t = 0; t < T; ++t) {
            float e = expf(av[t] - mx);
            av[t] = e;
            den += e;
        }
        for (int s = o0 + T * 64 + lane; s < o1; s += 64)
            den += expf((float)alpha[s] - mx);
#pragma unroll
        for (int o = 1; o < 64; o <<= 1) den += __shfl_xor(den, o);
        float di = 1.0f / (den + SMEPS);

        float acc0 = 0.f, acc1 = 0.f;
#pragma unroll
        for (int t = 0; t < T; ++t) {
            int base = o0 + t * 64;
            if (base >= o1) break;
            int c2 = min(64, o1 - base);
            int j = 0;
            for (; j + 4 <= c2; j += 4) {
                float w0 = __shfl(av[t],  j,     64);
                int  sn0 = __shfl(idx[t], j,     64);
                float w1 = __shfl(av[t],  j + 1, 64);
                int  sn1 = __shfl(idx[t], j + 1, 64);
                float w2 = __shfl(av[t],  j + 2, 64);
                int  sn2 = __shfl(idx[t], j + 2, 64);
                float w3 = __shfl(av[t],  j + 3, 64);
                int  sn3 = __shfl(idx[t], j + 3, 64);
                float x0 = (float)xp[(long)sn0 * 64 + lane];
                float x1 = (float)xp[(long)sn1 * 64 + lane];
                float x2 = (float)xp[(long)sn2 * 64 + lane];
                float x3 = (float)xp[(long)sn3 * 64 + lane];
                acc0 = fmaf(w0, x0, acc0);
                acc1 = fmaf(w1, x1, acc1);
                acc0 = fmaf(w2, x2, acc0);
                acc1 = fmaf(w3, x3, acc1);
            }
            for (; j < c2; ++j) {
                float w  = __shfl(av[t],  j, 64);
                int   sn = __shfl(idx[t], j, 64);
                acc0 = fmaf(w, (float)xp[(long)sn * 64 + lane], acc0);
            }
        }
        for (int s = o0 + T * 64; s < o1; ++s) {
            float w  = expf((float)alpha[s] - mx);
            int   sn = csr_src[s];
            acc0 = fmaf(w, (float)xp[(long)sn * 64 + lane], acc0);
        }
        out[(long)gw * 64 + lane] = (f16)((acc0 + acc1) * di);
    }
}

// ---------------------------------------------------------------------------
// BatchNorm (eval stats) + ELU — per-block partials, NO float atomics.
// GAT bias b skipped: cancels exactly in (x - mean).
// ---------------------------------------------------------------------------
__global__ void k_bnstats(const f16* __restrict__ x, int width,
                          float* __restrict__ s1p, float* __restrict__ s2p) {
    __shared__ float sa[256], sb[256];
    int col  = threadIdx.x % width;
    int rsub = threadIdx.x / width;
    int rpb  = 256 / width;
    float a = 0.f, b = 0.f;
    for (int r = blockIdx.x * rpb + rsub; r < NNODES; r += gridDim.x * rpb) {
        float v = (float)x[(long)r * width + col];
        a += v; b += v * v;
    }
    if (rpb == 1) {
        s1p[blockIdx.x * width + col] = a;
        s2p[blockIdx.x * width + col] = b;
    } else {
        sa[threadIdx.x] = a;
        sb[threadIdx.x] = b;
        __syncthreads();
        if (rsub == 0) {
            for (int k = 1; k < rpb; ++k) {
                a += sa[col + k * width];
                b += sb[col + k * width];
            }
            s1p[blockIdx.x * width + col] = a;
            s2p[blockIdx.x * width + col] = b;
        }
    }
}

__global__ void k_bnfin(const float* __restrict__ s1p, const float* __restrict__ s2p,
                        const float* __restrict__ g, const float* __restrict__ be,
                        int width, float* __restrict__ scale, float* __restrict__ shift) {
    int c = threadIdx.x;
    if (c >= width) return;
    float s1 = 0.f, s2 = 0.f;
    for (int k = 0; k < BNB; ++k) {          // coalesced: consecutive c per k
        s1 += s1p[k * width + c];
        s2 += s2p[k * width + c];
    }
    float mu  = s1 * (1.0f / NNODES);
    float var = s2 * (1.0f / NNODES) - mu * mu;
    float sc  = g[c] * rsqrtf(var + BNEPS);
    scale[c] = sc;
    shift[c] = be[c] - mu * sc;
}

__global__ void k_bnelu_h(const f16* __restrict__ xin, f16* __restrict__ xout,
                          const float* __restrict__ scale, const float* __restrict__ shift,
                          int width) {
    long i = (long)(blockIdx.x * blockDim.x + threadIdx.x);
    long total = (long)NNODES * width;
    if (i * 4 >= total) return;
    f16x4 v4 = *(const f16x4*)&xin[i * 4];
    int c = (int)((i * 4) % width);      // width % 4 == 0 -> no row crossing
    float4 sc = *(const float4*)&scale[c];
    float4 sh = *(const float4*)&shift[c];
    float y0 = (float)v4[0] * sc.x + sh.x;
    float y1 = (float)v4[1] * sc.y + sh.y;
    float y2 = (float)v4[2] * sc.z + sh.z;
    float y3 = (float)v4[3] * sc.w + sh.w;
    y0 = (y0 > 0.f) ? y0 : expm1f(y0);
    y1 = (y1 > 0.f) ? y1 : expm1f(y1);
    y2 = (y2 > 0.f) ? y2 : expm1f(y2);
    y3 = (y3 > 0.f) ? y3 : expm1f(y3);
    f16x4 o = {(f16)y0, (f16)y1, (f16)y2, (f16)y3};
    *(f16x4*)&xout[i * 4] = o;
}

// out[n] = sigmoid(<h[n,:], linW> + linB) — one wave per node
__global__ __launch_bounds__(256) void k_final(const f16* __restrict__ h,
                                               const float* __restrict__ linW,
                                               const float* __restrict__ linB,
                                               float* __restrict__ out) {
    int gw   = (blockIdx.x * blockDim.x + threadIdx.x) >> 6;
    int lane = threadIdx.x & 63;
    if (gw >= NNODES) return;
    float v = (float)h[(long)gw * 64 + lane] * linW[lane];
    for (int o = 32; o > 0; o >>= 1) v += __shfl_xor(v, o);
    if (lane == 0) out[gw] = 1.0f / (1.0f + expf(-(v + linB[0])));
}

// ---------------------------------------------------------------------------
extern "C" void kernel_launch(void* const* d_in, const int* in_sizes, int n_in,
                              void* d_out, int out_size, void* d_ws, size_t ws_size,
                              hipStream_t stream) {
    (void)in_sizes; (void)n_in; (void)out_size; (void)ws_size;
    const float* x    = (const float*)d_in[0];
    const float* cdk  = (const float*)d_in[1];
    const int*   esrc = (const int*)d_in[2];
    const int*   edst = (const int*)d_in[3];
    const float* ea   = (const float*)d_in[4];
    const float* W[3]   = {(const float*)d_in[5],  (const float*)d_in[13], (const float*)d_in[21]};
    const float* as_[3] = {(const float*)d_in[6],  (const float*)d_in[14], (const float*)d_in[22]};
    const float* ad_[3] = {(const float*)d_in[7],  (const float*)d_in[15], (const float*)d_in[23]};
    const float* We_[3] = {(const float*)d_in[8],  (const float*)d_in[16], (const float*)d_in[24]};
    const float* ae_[3] = {(const float*)d_in[9],  (const float*)d_in[17], (const float*)d_in[25]};
    // b{i} (d_in[10/18/26]) skipped: exactly cancels in BatchNorm
    const float* g_[3]  = {(const float*)d_in[11], (const float*)d_in[19], (const float*)d_in[27]};
    const float* be_[3] = {(const float*)d_in[12], (const float*)d_in[20], (const float*)d_in[28]};
    const float* linW = (const float*)d_in[29];
    const float* linB = (const float*)d_in[30];
    float* out = (float*)d_out;

    // workspace layout. Zero region (padded atomic counters) FIRST -> 1 memset.
    char* base = (char*)d_ws;
    size_t p = 0;
    auto alloc = [&](size_t bytes) -> void* {
        void* r = base + p;
        p = (p + bytes + 255) & ~(size_t)255;
        return r;
    };
    // --- zero region (one counter per 128B line) ---
    int*   deg     = (int*)alloc((size_t)NNODES * CPAD * 4);
    int*   cursor  = (int*)alloc((size_t)NNODES * CPAD * 4);
    size_t zero_bytes = p;
    // --- rest (fully written before read; no zero-init needed) ---
    int*   off     = (int*)alloc((size_t)(NNODES + 1) * 4);
    int*   partials= (int*)alloc((size_t)SCANB * 4);
    float* eapart  = (float*)alloc((size_t)EASUMB * EDIM * 4);
    float* s1p     = (float*)alloc((size_t)BNB * 256 * 4);
    float* s2p     = (float*)alloc((size_t)BNB * 256 * 4);
    int*   csr_src = (int*)alloc((size_t)ETOT * 4);
    int*   perm    = (int*)alloc((size_t)ETOT * 4);
    f16*   alpha   = (f16*)alloc((size_t)ETOT * 4 * 2);
    float* als     = (float*)alloc((size_t)NNODES * 4 * 4);
    float* ald     = (float*)alloc((size_t)NNODES * 4 * 4);
    float* VeAll   = (float*)alloc((size_t)3 * 48 * 4);
    float* laAll   = (float*)alloc((size_t)3 * 4 * 4);
    float* scale   = (float*)alloc(256 * 4);
    float* shift   = (float*)alloc(256 * 4);
    f16*   Wt[3];
    Wt[0]          = (f16*)alloc((size_t)256 * 256 * 2);
    Wt[1]          = (f16*)alloc((size_t)256 * 256 * 2);
    Wt[2]          = (f16*)alloc((size_t)64 * 256 * 2);
    f16*   bufA_h  = (f16*)alloc((size_t)NNODES * 256 * 2);   // GEMM A input
    f16*   bufXp_h = (f16*)alloc((size_t)NNODES * 256 * 2);   // GEMM output (xp)
    f16*   bufC_h  = (f16*)alloc((size_t)NNODES * 256 * 2);   // agg output (fp16)

    hipMemsetAsync(base, 0, zero_bytes, stream);

    int eb = (ETOT + 255) / 256;
    k_deg<<<eb, 256, 0, stream>>>(edst, deg);
    k_easum<<<EASUMB, 256, 0, stream>>>(ea, eapart);
    k_scan1<<<SCANB, 256, 0, stream>>>(deg, off, partials);
    k_scan2<<<1, 256, 0, stream>>>(partials, off);
    k_scan3<<<SCANB, 256, 0, stream>>>(off, partials);
    k_scatter<<<eb, 256, 0, stream>>>(esrc, edst, off, cursor, csr_src, perm);
    k_concat_h<<<(NNODES * 256 + 255) / 256, 256, 0, stream>>>(x, cdk, bufA_h);
    k_wcvt_all<<<576, 256, 0, stream>>>(W[0], W[1], W[2], Wt[0], Wt[1], Wt[2]);
    k_ve_all<<<3, 64, 0, stream>>>(We_[0], ae_[0], We_[1], ae_[1], We_[2], ae_[2],
                                   eapart, VeAll, laAll);

    const int nodeblocks = (NNODES * 64) / 256;   // wave per node, 4 waves/block
    const int mblocks = (NNODES + 127) / 128;     // 391

    for (int l = 0; l < 3; ++l) {
        const int H  = (l == 2) ? 1 : 4;
        const int NC = H * 64;
        const float* Ve  = VeAll + l * 48;
        const float* la  = laAll + l * 4;
        dim3 gg(mblocks, NC / 64);
        k_gemm_h<<<gg, 256, 0, stream>>>(bufA_h, Wt[l], bufXp_h,
                                         as_[l], ad_[l], als, ald, NNODES, NC, H);
        if (H == 4) {
            k_edge<4><<<eb, 256, 0, stream>>>(ea, esrc, edst, als, ald, Ve, la, perm, alpha);
            k_agg<4><<<nodeblocks, 256, 0, stream>>>(bufXp_h, alpha, off, csr_src, bufC_h);
        } else {
            k_edge<1><<<eb, 256, 0, stream>>>(ea, esrc, edst, als, ald, Ve, la, perm, alpha);
            k_agg<1><<<nodeblocks, 256, 0, stream>>>(bufXp_h, alpha, off, csr_src, bufC_h);
        }
        k_bnstats<<<BNB, 256, 0, stream>>>(bufC_h, NC, s1p, s2p);
        k_bnfin<<<1, 256, 0, stream>>>(s1p, s2p, g_[l], be_[l], NC, scale, shift);
        k_bnelu_h<<<(NNODES * NC / 4 + 255) / 256, 256, 0, stream>>>(bufC_h, bufA_h, scale, shift, NC);
    }
    k_final<<<nodeblocks, 256, 0, stream>>>(bufA_h, linW, linB, out);
}

// Round 18
// 582.450 us; speedup vs baseline: 1.0944x; 1.0944x over previous
//
#include <hip/hip_runtime.h>
#include <math.h>

// Problem constants (match reference)
#define NNODES 50000
#define NEDGES 800000
#define ETOT   (NNODES + NEDGES)   // 850000 edges incl. self-loops
#define EDIM   10
#define SMEPS  1e-16f
#define BNEPS  1e-5f
#define NSLOPE 0.2f

#define EASUMB 256                      // easum partial blocks
#define BNB    256                      // bnstats partial blocks
#define CAP    64                       // padded CSR capacity per node

typedef _Float16 f16;
typedef f16 f16x8 __attribute__((ext_vector_type(8)));
typedef f16 f16x4 __attribute__((ext_vector_type(4)));
typedef float f32x4 __attribute__((ext_vector_type(4)));

// ---------------------------------------------------------------------------
// CSR build in ONE atomic pass (no histogram+scan+scatter chain):
// slot = dst*CAP + pos, pos = atomicAdd(deg[dst]). Max degree for this
// problem is ~43 << CAP=64; edges past CAP go to an overflow list so
// correctness is unconditional (k_agg folds them in; cold path in practice).
// ---------------------------------------------------------------------------
__global__ void k_place(const int* __restrict__ esrc, const int* __restrict__ edst,
                        int* __restrict__ deg, int* __restrict__ csr_src,
                        int* __restrict__ perm, int* __restrict__ ovf_cnt,
                        int* __restrict__ ovf_src, int* __restrict__ ovf_dst) {
    int e = blockIdx.x * blockDim.x + threadIdx.x;
    if (e >= ETOT) return;
    int s, d;
    if (e < NEDGES) { s = esrc[e]; d = edst[e]; }
    else            { s = d = e - NEDGES; }      // self-loop
    int pos = atomicAdd(&deg[d], 1);
    if (pos < CAP) {
        int slot = d * CAP + pos;
        csr_src[slot] = s;
        perm[e] = slot;
    } else {                                     // never in practice
        int k = atomicAdd(ovf_cnt, 1);
        ovf_src[k] = s;
        ovf_dst[k] = d;
        perm[e] = -1 - k;
    }
}

// edge_attr column sums -> per-block partials (NO global float atomics)
__global__ void k_easum(const float* __restrict__ ea, float* __restrict__ part) {
    float acc[EDIM];
#pragma unroll
    for (int d = 0; d < EDIM; ++d) acc[d] = 0.f;
    int tid = blockIdx.x * blockDim.x + threadIdx.x;
    const int np = NEDGES / 2;   // 400000 pairs (NEDGES even)
    for (int p = tid; p < np; p += gridDim.x * blockDim.x) {
        const float4* q = (const float4*)&ea[(long)p * 20];
        float4 v0 = q[0], v1 = q[1], v2 = q[2], v3 = q[3], v4 = q[4];
        acc[0] += v0.x + v2.z;
        acc[1] += v0.y + v2.w;
        acc[2] += v0.z + v3.x;
        acc[3] += v0.w + v3.y;
        acc[4] += v1.x + v3.z;
        acc[5] += v1.y + v3.w;
        acc[6] += v1.z + v4.x;
        acc[7] += v1.w + v4.y;
        acc[8] += v2.x + v4.z;
        acc[9] += v2.y + v4.w;
    }
    __shared__ float sm[256];
    for (int d = 0; d < EDIM; ++d) {
        sm[threadIdx.x] = acc[d];
        __syncthreads();
        for (int s = 128; s > 0; s >>= 1) {
            if (threadIdx.x < s) sm[threadIdx.x] += sm[threadIdx.x + s];
            __syncthreads();
        }
        if (threadIdx.x == 0) part[blockIdx.x * EDIM + d] = sm[0];
        __syncthreads();
    }
}

// h0 = concat(x[N,40], cdk[N,200]) -> fp16 [N,256], cols 240..255 zero-padded
__global__ void k_concat_h(const float* __restrict__ x, const float* __restrict__ cdk,
                           f16* __restrict__ out) {
    int i = blockIdx.x * blockDim.x + threadIdx.x;
    if (i >= NNODES * 256) return;
    int n = i >> 8, j = i & 255;
    float v = (j < 40) ? x[n * 40 + j] : (j < 240) ? cdk[n * 200 + (j - 40)] : 0.f;
    out[i] = (f16)v;
}

// All three weight transposes in one launch: Wt[n][k] = fp16(W[k][n]), k padded
__global__ void k_wcvt_all(const float* __restrict__ W0, const float* __restrict__ W1,
                           const float* __restrict__ W2, f16* __restrict__ Wt0,
                           f16* __restrict__ Wt1, f16* __restrict__ Wt2) {
    int i = blockIdx.x * blockDim.x + threadIdx.x;
    const float* W; f16* Wt; int K, NC, j;
    if (i < 65536)       { W = W0; Wt = Wt0; K = 240; NC = 256; j = i; }
    else if (i < 131072) { W = W1; Wt = Wt1; K = 256; NC = 256; j = i - 65536; }
    else if (i < 147456) { W = W2; Wt = Wt2; K = 256; NC = 64;  j = i - 131072; }
    else return;
    int n = j >> 8, k = j & 255;
    Wt[j] = (k < K) ? (f16)W[k * NC + n] : (f16)0.f;
}

// ---------------------------------------------------------------------------
// fp16 MFMA GEMM + fused attention-coefficient epilogue.
// ---------------------------------------------------------------------------
#define GM_LDS 40
__global__ __launch_bounds__(256) void k_gemm_h(const f16* __restrict__ A,
                                                const f16* __restrict__ Bt,
                                                f16* __restrict__ C,
                                                const float* __restrict__ a_s,
                                                const float* __restrict__ a_d,
                                                float* __restrict__ als,
                                                float* __restrict__ ald,
                                                int M, int NC, int H) {
    __shared__ f16 As[128 * GM_LDS];
    __shared__ f16 Bs[64 * GM_LDS];
    const int t    = threadIdx.x;
    const int w    = t >> 6;
    const int lane = t & 63;
    const int row0 = blockIdx.x * 128;
    const int col0 = blockIdx.y * 64;

    const int ar = t >> 1;              // A stage: row 0..127
    const int ak = (t & 1) * 16;        //          16-half chunk offset 0/16
    const int bn = t >> 2;              // B stage: n 0..63
    const int bk = (t & 3) * 8;         //          k-offset 0/8/16/24

    const int l16 = lane & 15;
    const int kg  = lane >> 4;

    f32x4 acc[2][4];
#pragma unroll
    for (int i = 0; i < 2; ++i)
#pragma unroll
        for (int j = 0; j < 4; ++j) acc[i][j] = {0.f, 0.f, 0.f, 0.f};

    for (int k0 = 0; k0 < 256; k0 += 32) {
        f16x8 av0, av1;
#pragma unroll
        for (int i = 0; i < 8; ++i) { av0[i] = (f16)0.f; av1[i] = (f16)0.f; }
        if (row0 + ar < M) {
            const f16* ap = &A[(long)(row0 + ar) * 256 + k0 + ak];
            av0 = *(const f16x8*)ap;
            av1 = *(const f16x8*)(ap + 8);
        }
        *(f16x8*)&As[ar * GM_LDS + ak]     = av0;
        *(f16x8*)&As[ar * GM_LDS + ak + 8] = av1;
        f16x8 bv = *(const f16x8*)&Bt[(long)(col0 + bn) * 256 + k0 + bk];
        *(f16x8*)&Bs[bn * GM_LDS + bk] = bv;
        __syncthreads();

        f16x8 afr[2], bfr[4];
#pragma unroll
        for (int mi = 0; mi < 2; ++mi)
            afr[mi] = *(const f16x8*)&As[(w * 32 + mi * 16 + l16) * GM_LDS + kg * 8];
#pragma unroll
        for (int ni = 0; ni < 4; ++ni)
            bfr[ni] = *(const f16x8*)&Bs[(ni * 16 + l16) * GM_LDS + kg * 8];
#pragma unroll
        for (int mi = 0; mi < 2; ++mi)
#pragma unroll
            for (int ni = 0; ni < 4; ++ni)
                acc[mi][ni] = __builtin_amdgcn_mfma_f32_16x16x32_f16(
                    afr[mi], bfr[ni], acc[mi][ni], 0, 0, 0);
        __syncthreads();
    }

    // C write
#pragma unroll
    for (int mi = 0; mi < 2; ++mi)
#pragma unroll
        for (int ni = 0; ni < 4; ++ni)
#pragma unroll
            for (int j = 0; j < 4; ++j) {
                int r = row0 + w * 32 + mi * 16 + kg * 4 + j;
                if (r < M) C[(long)r * NC + col0 + ni * 16 + l16] = (f16)acc[mi][ni][j];
            }

    // fused al_s/al_d: this block's 64 cols = head hidx fully
    const int hidx = blockIdx.y;
    float asv[4], adv[4];
#pragma unroll
    for (int ni = 0; ni < 4; ++ni) {
        asv[ni] = a_s[hidx * 64 + ni * 16 + l16];
        adv[ni] = a_d[hidx * 64 + ni * 16 + l16];
    }
#pragma unroll
    for (int mi = 0; mi < 2; ++mi)
#pragma unroll
        for (int j = 0; j < 4; ++j) {
            float ps = acc[mi][0][j] * asv[0] + acc[mi][1][j] * asv[1]
                     + acc[mi][2][j] * asv[2] + acc[mi][3][j] * asv[3];
            float pd = acc[mi][0][j] * adv[0] + acc[mi][1][j] * adv[1]
                     + acc[mi][2][j] * adv[2] + acc[mi][3][j] * adv[3];
#pragma unroll
            for (int o = 1; o < 16; o <<= 1) {
                ps += __shfl_xor(ps, o);
                pd += __shfl_xor(pd, o);
            }
            int r = row0 + w * 32 + mi * 16 + kg * 4 + j;
            if (l16 == 0 && r < M) {
                als[(long)r * H + hidx] = ps;
                ald[(long)r * H + hidx] = pd;
            }
        }
}

// All 3 layers' Ve[d,h] and loop_al[h] in one launch (block = layer, 1 wave).
__global__ void k_ve_all(const float* __restrict__ We0, const float* __restrict__ ae0,
                         const float* __restrict__ We1, const float* __restrict__ ae1,
                         const float* __restrict__ We2, const float* __restrict__ ae2,
                         const float* __restrict__ eapart,
                         float* __restrict__ VeAll, float* __restrict__ laAll) {
    int l = blockIdx.x;
    const float* We = (l == 0) ? We0 : (l == 1) ? We1 : We2;
    const float* ae = (l == 0) ? ae0 : (l == 1) ? ae1 : ae2;
    int H = (l == 2) ? 1 : 4;
    float* Ve = VeAll + l * 48;
    float* la = laAll + l * 4;
    int t = threadIdx.x;          // 0..63, one wave

    float ac[EDIM];
#pragma unroll
    for (int d = 0; d < EDIM; ++d) ac[d] = 0.f;
    for (int r = t; r < EASUMB; r += 64) {
#pragma unroll
        for (int d = 0; d < EDIM; ++d) ac[d] += eapart[r * EDIM + d];
    }
#pragma unroll
    for (int o = 1; o < 64; o <<= 1) {
#pragma unroll
        for (int d = 0; d < EDIM; ++d) ac[d] += __shfl_xor(ac[d], o);
    }

    if (t < EDIM * H) {
        int d = t / H, h = t % H;
        float s = 0.f;
        for (int c = 0; c < 64; ++c) s += We[d * (H * 64) + h * 64 + c] * ae[h * 64 + c];
        Ve[d * H + h] = s;
    }
    __syncthreads();
    if (t < H) {
        float s = 0.f;
        for (int d = 0; d < EDIM; ++d) s += (ac[d] * (1.0f / NEDGES)) * Ve[d * H + t];
        la[t] = s;
    }
}

// Edge-parallel alpha (fp16 logits), written at padded slot via perm.
// Negative perm -> overflow entry (cold path).
template <int H>
__global__ void k_edge(const float* __restrict__ ea, const int* __restrict__ esrc,
                       const int* __restrict__ edst, const float* __restrict__ als,
                       const float* __restrict__ ald, const float* __restrict__ Ve,
                       const float* __restrict__ loop_al, const int* __restrict__ perm,
                       f16* __restrict__ alpha, f16* __restrict__ alpha_ovf) {
    int e = blockIdx.x * blockDim.x + threadIdx.x;
    if (e >= ETOT) return;
    int s, d;
    float ale[H];
    if (e < NEDGES) {
        s = esrc[e]; d = edst[e];
#pragma unroll
        for (int h = 0; h < H; ++h) ale[h] = 0.f;
#pragma unroll
        for (int dd = 0; dd < EDIM; ++dd) {
            float v = ea[(long)e * EDIM + dd];
#pragma unroll
            for (int h = 0; h < H; ++h) ale[h] = fmaf(v, Ve[dd * H + h], ale[h]);
        }
    } else {
        s = d = e - NEDGES;
#pragma unroll
        for (int h = 0; h < H; ++h) ale[h] = loop_al[h];
    }
    int slot = perm[e];
    f16* dst = (slot >= 0) ? &alpha[(long)slot * H]
                           : &alpha_ovf[(long)(-1 - slot) * H];
#pragma unroll
    for (int h = 0; h < H; ++h) {
        float a = als[s * H + h] + ald[d * H + h] + ale[h];
        a = (a > 0.f) ? a : NSLOPE * a;
        dst[h] = (f16)a;
    }
}

// ---------------------------------------------------------------------------
// Node-parallel softmax + aggregation on the PADDED CSR (o0 = gw*CAP,
// cnt = min(deg,CAP)). Overflow entries (deg>CAP, never in practice) are
// folded in after the wave reductions. 4-deep MLP gather (measured optimum).
// ---------------------------------------------------------------------------
template <int H>
__global__ __launch_bounds__(256) void k_agg(const f16* __restrict__ xp,
                                             const f16* __restrict__ alpha,
                                             const int* __restrict__ deg,
                                             const int* __restrict__ csr_src,
                                             const int* __restrict__ ovf_cnt,
                                             const int* __restrict__ ovf_src,
                                             const int* __restrict__ ovf_dst,
                                             const f16* __restrict__ alpha_ovf,
                                             f16* __restrict__ out) {
    int gw   = (blockIdx.x * blockDim.x + threadIdx.x) >> 6;
    int lane = threadIdx.x & 63;
    if (gw >= NNODES) return;
    int dcount = deg[gw];
    int cnt = min(dcount, CAP);
    int o0 = gw * CAP;
    int o1 = o0 + cnt;
    bool ovf = (dcount > CAP);

    if constexpr (H == 4) {
        constexpr int T = 4;                 // covers CAP=64 edges
        int h  = lane >> 4;
        int il = lane & 15;
        int glane = lane & 48;               // first lane of this head's group

        // pass 1: distributed load of alpha + csr_src (register-cached)
        float av[T];
        int   idx[T];
        float mx = -INFINITY;
#pragma unroll
        for (int t = 0; t < T; ++t) {
            int s = o0 + t * 16 + il;
            bool ok = (s < o1);
            float a = ok ? (float)alpha[(long)s * 4 + h] : -INFINITY;
            idx[t] = ok ? csr_src[s] : 0;
            av[t] = a;
            mx = fmaxf(mx, a);
        }
#pragma unroll
        for (int o = 1; o < 16; o <<= 1) mx = fmaxf(mx, __shfl_xor(mx, o));
        if (ovf) {                            // cold path: fold overflow max
            int nov = *ovf_cnt;
            for (int k = 0; k < nov; ++k)
                if (ovf_dst[k] == gw)
                    mx = fmaxf(mx, (float)alpha_ovf[(long)k * 4 + h]);
        }

        // pass 2: exp from registers, group-reduced denominator
        float den = 0.f;
#pragma unroll
        for (int t = 0; t < T; ++t) {
            float e = expf(av[t] - mx);      // exp(-inf)=0 handles padding
            av[t] = e;
            den += e;
        }
#pragma unroll
        for (int o = 1; o < 16; o <<= 1) den += __shfl_xor(den, o);
        if (ovf) {                            // cold path: fold overflow den
            int nov = *ovf_cnt;
            for (int k = 0; k < nov; ++k)
                if (ovf_dst[k] == gw)
                    den += expf((float)alpha_ovf[(long)k * 4 + h] - mx);
        }
        float di = 1.0f / (den + SMEPS);

        // pass 3: weighted gather, 4-way unrolled (4 loads in flight)
        float4 acc0 = make_float4(0.f, 0.f, 0.f, 0.f);
        float4 acc1 = make_float4(0.f, 0.f, 0.f, 0.f);
#pragma unroll
        for (int t = 0; t < T; ++t) {
            int base = t * 16;
            if (base >= cnt) break;
            int c2 = min(16, cnt - base);
            int j = 0;
            for (; j + 4 <= c2; j += 4) {
                float w0 = __shfl(av[t],  glane + j,     64);
                int  sn0 = __shfl(idx[t], glane + j,     64);
                float w1 = __shfl(av[t],  glane + j + 1, 64);
                int  sn1 = __shfl(idx[t], glane + j + 1, 64);
                float w2 = __shfl(av[t],  glane + j + 2, 64);
                int  sn2 = __shfl(idx[t], glane + j + 2, 64);
                float w3 = __shfl(av[t],  glane + j + 3, 64);
                int  sn3 = __shfl(idx[t], glane + j + 3, 64);
                f16x4 x0 = *(const f16x4*)&xp[(long)sn0 * 256 + lane * 4];
                f16x4 x1 = *(const f16x4*)&xp[(long)sn1 * 256 + lane * 4];
                f16x4 x2 = *(const f16x4*)&xp[(long)sn2 * 256 + lane * 4];
                f16x4 x3 = *(const f16x4*)&xp[(long)sn3 * 256 + lane * 4];
                acc0.x = fmaf(w0, (float)x0[0], acc0.x);
                acc0.y = fmaf(w0, (float)x0[1], acc0.y);
                acc0.z = fmaf(w0, (float)x0[2], acc0.z);
                acc0.w = fmaf(w0, (float)x0[3], acc0.w);
                acc1.x = fmaf(w1, (float)x1[0], acc1.x);
                acc1.y = fmaf(w1, (float)x1[1], acc1.y);
                acc1.z = fmaf(w1, (float)x1[2], acc1.z);
                acc1.w = fmaf(w1, (float)x1[3], acc1.w);
                acc0.x = fmaf(w2, (float)x2[0], acc0.x);
                acc0.y = fmaf(w2, (float)x2[1], acc0.y);
                acc0.z = fmaf(w2, (float)x2[2], acc0.z);
                acc0.w = fmaf(w2, (float)x2[3], acc0.w);
                acc1.x = fmaf(w3, (float)x3[0], acc1.x);
                acc1.y = fmaf(w3, (float)x3[1], acc1.y);
                acc1.z = fmaf(w3, (float)x3[2], acc1.z);
                acc1.w = fmaf(w3, (float)x3[3], acc1.w);
            }
            for (; j < c2; ++j) {
                float w  = __shfl(av[t],  glane + j, 64);
                int   sn = __shfl(idx[t], glane + j, 64);
                f16x4 xh = *(const f16x4*)&xp[(long)sn * 256 + lane * 4];
                acc0.x = fmaf(w, (float)xh[0], acc0.x);
                acc0.y = fmaf(w, (float)xh[1], acc0.y);
                acc0.z = fmaf(w, (float)xh[2], acc0.z);
                acc0.w = fmaf(w, (float)xh[3], acc0.w);
            }
        }
        if (ovf) {                            // cold path: fold overflow edges
            int nov = *ovf_cnt;
            for (int k = 0; k < nov; ++k) {
                if (ovf_dst[k] == gw) {
                    float w  = expf((float)alpha_ovf[(long)k * 4 + h] - mx);
                    int   sn = ovf_src[k];
                    f16x4 xh = *(const f16x4*)&xp[(long)sn * 256 + lane * 4];
                    acc0.x = fmaf(w, (float)xh[0], acc0.x);
                    acc0.y = fmaf(w, (float)xh[1], acc0.y);
                    acc0.z = fmaf(w, (float)xh[2], acc0.z);
                    acc0.w = fmaf(w, (float)xh[3], acc0.w);
                }
            }
        }
        f16x4 o4 = {(f16)((acc0.x + acc1.x) * di), (f16)((acc0.y + acc1.y) * di),
                    (f16)((acc0.z + acc1.z) * di), (f16)((acc0.w + acc1.w) * di)};
        *(f16x4*)&out[(long)gw * 256 + lane * 4] = o4;
    } else {
        // H == 1: one lane per column, CAP=64 edges covered in one stripe
        int s = o0 + lane;
        bool ok = (lane < cnt);
        float av0 = ok ? (float)alpha[s] : -INFINITY;
        int   id0 = ok ? csr_src[s] : 0;
        float mx = av0;
#pragma unroll
        for (int o = 1; o < 64; o <<= 1) mx = fmaxf(mx, __shfl_xor(mx, o));
        if (ovf) {
            int nov = *ovf_cnt;
            for (int k = 0; k < nov; ++k)
                if (ovf_dst[k] == gw)
                    mx = fmaxf(mx, (float)alpha_ovf[k]);
        }
        float e0 = expf(av0 - mx);
        float den = e0;
#pragma unroll
        for (int o = 1; o < 64; o <<= 1) den += __shfl_xor(den, o);
        if (ovf) {
            int nov = *ovf_cnt;
            for (int k = 0; k < nov; ++k)
                if (ovf_dst[k] == gw)
                    den += expf((float)alpha_ovf[k] - mx);
        }
        float di = 1.0f / (den + SMEPS);

        float acc0 = 0.f, acc1 = 0.f;
        int j = 0;
        for (; j + 4 <= cnt; j += 4) {
            float w0 = __shfl(e0,  j,     64);
            int  sn0 = __shfl(id0, j,     64);
            float w1 = __shfl(e0,  j + 1, 64);
            int  sn1 = __shfl(id0, j + 1, 64);
            float w2 = __shfl(e0,  j + 2, 64);
            int  sn2 = __shfl(id0, j + 2, 64);
            float w3 = __shfl(e0,  j + 3, 64);
            int  sn3 = __shfl(id0, j + 3, 64);
            float x0 = (float)xp[(long)sn0 * 64 + lane];
            float x1 = (float)xp[(long)sn1 * 64 + lane];
            float x2 = (float)xp[(long)sn2 * 64 + lane];
            float x3 = (float)xp[(long)sn3 * 64 + lane];
            acc0 = fmaf(w0, x0, acc0);
            acc1 = fmaf(w1, x1, acc1);
            acc0 = fmaf(w2, x2, acc0);
            acc1 = fmaf(w3, x3, acc1);
        }
        for (; j < cnt; ++j) {
            float w  = __shfl(e0,  j, 64);
            int   sn = __shfl(id0, j, 64);
            acc0 = fmaf(w, (float)xp[(long)sn * 64 + lane], acc0);
        }
        if (ovf) {
            int nov = *ovf_cnt;
            for (int k = 0; k < nov; ++k) {
                if (ovf_dst[k] == gw) {
                    float w  = expf((float)alpha_ovf[k] - mx);
                    int   sn = ovf_src[k];
                    acc0 = fmaf(w, (float)xp[(long)sn * 64 + lane], acc0);
                }
            }
        }
        out[(long)gw * 64 + lane] = (f16)((acc0 + acc1) * di);
    }
}

// ---------------------------------------------------------------------------
// BatchNorm (eval stats) + ELU — per-block partials, NO float atomics.
// GAT bias b skipped: cancels exactly in (x - mean).
// ---------------------------------------------------------------------------
__global__ void k_bnstats(const f16* __restrict__ x, int width,
                          float* __restrict__ s1p, float* __restrict__ s2p) {
    __shared__ float sa[256], sb[256];
    int col  = threadIdx.x % width;
    int rsub = threadIdx.x / width;
    int rpb  = 256 / width;
    float a = 0.f, b = 0.f;
    for (int r = blockIdx.x * rpb + rsub; r < NNODES; r += gridDim.x * rpb) {
        float v = (float)x[(long)r * width + col];
        a += v; b += v * v;
    }
    if (rpb == 1) {
        s1p[blockIdx.x * width + col] = a;
        s2p[blockIdx.x * width + col] = b;
    } else {
        sa[threadIdx.x] = a;
        sb[threadIdx.x] = b;
        __syncthreads();
        if (rsub == 0) {
            for (int k = 1; k < rpb; ++k) {
                a += sa[col + k * width];
                b += sb[col + k * width];
            }
            s1p[blockIdx.x * width + col] = a;
            s2p[blockIdx.x * width + col] = b;
        }
    }
}

__global__ void k_bnfin(const float* __restrict__ s1p, const float* __restrict__ s2p,
                        const float* __restrict__ g, const float* __restrict__ be,
                        int width, float* __restrict__ scale, float* __restrict__ shift) {
    int c = threadIdx.x;
    if (c >= width) return;
    float s1 = 0.f, s2 = 0.f;
    for (int k = 0; k < BNB; ++k) {          // coalesced: consecutive c per k
        s1 += s1p[k * width + c];
        s2 += s2p[k * width + c];
    }
    float mu  = s1 * (1.0f / NNODES);
    float var = s2 * (1.0f / NNODES) - mu * mu;
    float sc  = g[c] * rsqrtf(var + BNEPS);
    scale[c] = sc;
    shift[c] = be[c] - mu * sc;
}

__global__ void k_bnelu_h(const f16* __restrict__ xin, f16* __restrict__ xout,
                          const float* __restrict__ scale, const float* __restrict__ shift,
                          int width) {
    long i = (long)(blockIdx.x * blockDim.x + threadIdx.x);
    long total = (long)NNODES * width;
    if (i * 4 >= total) return;
    f16x4 v4 = *(const f16x4*)&xin[i * 4];
    int c = (int)((i * 4) % width);      // width % 4 == 0 -> no row crossing
    float4 sc = *(const float4*)&scale[c];
    float4 sh = *(const float4*)&shift[c];
    float y0 = (float)v4[0] * sc.x + sh.x;
    float y1 = (float)v4[1] * sc.y + sh.y;
    float y2 = (float)v4[2] * sc.z + sh.z;
    float y3 = (float)v4[3] * sc.w + sh.w;
    y0 = (y0 > 0.f) ? y0 : expm1f(y0);
    y1 = (y1 > 0.f) ? y1 : expm1f(y1);
    y2 = (y2 > 0.f) ? y2 : expm1f(y2);
    y3 = (y3 > 0.f) ? y3 : expm1f(y3);
    f16x4 o = {(f16)y0, (f16)y1, (f16)y2, (f16)y3};
    *(f16x4*)&xout[i * 4] = o;
}

// out[n] = sigmoid(<h[n,:], linW> + linB) — one wave per node
__global__ __launch_bounds__(256) void k_final(const f16* __restrict__ h,
                                               const float* __restrict__ linW,
                                               const float* __restrict__ linB,
                                               float* __restrict__ out) {
    int gw   = (blockIdx.x * blockDim.x + threadIdx.x) >> 6;
    int lane = threadIdx.x & 63;
    if (gw >= NNODES) return;
    float v = (float)h[(long)gw * 64 + lane] * linW[lane];
    for (int o = 32; o > 0; o >>= 1) v += __shfl_xor(v, o);
    if (lane == 0) out[gw] = 1.0f / (1.0f + expf(-(v + linB[0])));
}

// ---------------------------------------------------------------------------
extern "C" void kernel_launch(void* const* d_in, const int* in_sizes, int n_in,
                              void* d_out, int out_size, void* d_ws, size_t ws_size,
                              hipStream_t stream) {
    (void)in_sizes; (void)n_in; (void)out_size; (void)ws_size;
    const float* x    = (const float*)d_in[0];
    const float* cdk  = (const float*)d_in[1];
    const int*   esrc = (const int*)d_in[2];
    const int*   edst = (const int*)d_in[3];
    const float* ea   = (const float*)d_in[4];
    const float* W[3]   = {(const float*)d_in[5],  (const float*)d_in[13], (const float*)d_in[21]};
    const float* as_[3] = {(const float*)d_in[6],  (const float*)d_in[14], (const float*)d_in[22]};
    const float* ad_[3] = {(const float*)d_in[7],  (const float*)d_in[15], (const float*)d_in[23]};
    const float* We_[3] = {(const float*)d_in[8],  (const float*)d_in[16], (const float*)d_in[24]};
    const float* ae_[3] = {(const float*)d_in[9],  (const float*)d_in[17], (const float*)d_in[25]};
    // b{i} (d_in[10/18/26]) skipped: exactly cancels in BatchNorm
    const float* g_[3]  = {(const float*)d_in[11], (const float*)d_in[19], (const float*)d_in[27]};
    const float* be_[3] = {(const float*)d_in[12], (const float*)d_in[20], (const float*)d_in[28]};
    const float* linW = (const float*)d_in[29];
    const float* linB = (const float*)d_in[30];
    float* out = (float*)d_out;

    // workspace layout. Zero region (deg + ovf_cnt) FIRST -> 1 small memset.
    char* base = (char*)d_ws;
    size_t p = 0;
    auto alloc = [&](size_t bytes) -> void* {
        void* r = base + p;
        p = (p + bytes + 255) & ~(size_t)255;
        return r;
    };
    // --- zero region ---
    int*   deg     = (int*)alloc((size_t)NNODES * 4);
    int*   ovf_cnt = (int*)alloc(4);
    size_t zero_bytes = p;
    // --- rest (fully written before read; no zero-init needed) ---
    float* eapart  = (float*)alloc((size_t)EASUMB * EDIM * 4);
    float* s1p     = (float*)alloc((size_t)BNB * 256 * 4);
    float* s2p     = (float*)alloc((size_t)BNB * 256 * 4);
    int*   csr_src = (int*)alloc((size_t)NNODES * CAP * 4);
    int*   perm    = (int*)alloc((size_t)ETOT * 4);
    f16*   alpha   = (f16*)alloc((size_t)NNODES * CAP * 4 * 2);
    int*   ovf_src = (int*)alloc((size_t)ETOT * 4);
    int*   ovf_dst = (int*)alloc((size_t)ETOT * 4);
    f16*   alpha_o = (f16*)alloc((size_t)ETOT * 4 * 2);
    float* als     = (float*)alloc((size_t)NNODES * 4 * 4);
    float* ald     = (float*)alloc((size_t)NNODES * 4 * 4);
    float* VeAll   = (float*)alloc((size_t)3 * 48 * 4);
    float* laAll   = (float*)alloc((size_t)3 * 4 * 4);
    float* scale   = (float*)alloc(256 * 4);
    float* shift   = (float*)alloc(256 * 4);
    f16*   Wt[3];
    Wt[0]          = (f16*)alloc((size_t)256 * 256 * 2);
    Wt[1]          = (f16*)alloc((size_t)256 * 256 * 2);
    Wt[2]          = (f16*)alloc((size_t)64 * 256 * 2);
    f16*   bufA_h  = (f16*)alloc((size_t)NNODES * 256 * 2);   // GEMM A input
    f16*   bufXp_h = (f16*)alloc((size_t)NNODES * 256 * 2);   // GEMM output (xp)
    f16*   bufC_h  = (f16*)alloc((size_t)NNODES * 256 * 2);   // agg output (fp16)

    hipMemsetAsync(base, 0, zero_bytes, stream);

    int eb = (ETOT + 255) / 256;
    k_place<<<eb, 256, 0, stream>>>(esrc, edst, deg, csr_src, perm,
                                    ovf_cnt, ovf_src, ovf_dst);
    k_easum<<<EASUMB, 256, 0, stream>>>(ea, eapart);
    k_concat_h<<<(NNODES * 256 + 255) / 256, 256, 0, stream>>>(x, cdk, bufA_h);
    k_wcvt_all<<<576, 256, 0, stream>>>(W[0], W[1], W[2], Wt[0], Wt[1], Wt[2]);
    k_ve_all<<<3, 64, 0, stream>>>(We_[0], ae_[0], We_[1], ae_[1], We_[2], ae_[2],
                                   eapart, VeAll, laAll);

    const int nodeblocks = (NNODES * 64) / 256;   // wave per node, 4 waves/block
    const int mblocks = (NNODES + 127) / 128;     // 391

    for (int l = 0; l < 3; ++l) {
        const int H  = (l == 2) ? 1 : 4;
        const int NC = H * 64;
        const float* Ve  = VeAll + l * 48;
        const float* la  = laAll + l * 4;
        dim3 gg(mblocks, NC / 64);
        k_gemm_h<<<gg, 256, 0, stream>>>(bufA_h, Wt[l], bufXp_h,
                                         as_[l], ad_[l], als, ald, NNODES, NC, H);
        if (H == 4) {
            k_edge<4><<<eb, 256, 0, stream>>>(ea, esrc, edst, als, ald, Ve, la,
                                              perm, alpha, alpha_o);
            k_agg<4><<<nodeblocks, 256, 0, stream>>>(bufXp_h, alpha, deg, csr_src,
                                                     ovf_cnt, ovf_src, ovf_dst,
                                                     alpha_o, bufC_h);
        } else {
            k_edge<1><<<eb, 256, 0, stream>>>(ea, esrc, edst, als, ald, Ve, la,
                                              perm, alpha, alpha_o);
            k_agg<1><<<nodeblocks, 256, 0, stream>>>(bufXp_h, alpha, deg, csr_src,
                                                     ovf_cnt, ovf_src, ovf_dst,
                                                     alpha_o, bufC_h);
        }
        k_bnstats<<<BNB, 256, 0, stream>>>(bufC_h, NC, s1p, s2p);
        k_bnfin<<<1, 256, 0, stream>>>(s1p, s2p, g_[l], be_[l], NC, scale, shift);
        k_bnelu_h<<<(NNODES * NC / 4 + 255) / 256, 256, 0, stream>>>(bufC_h, bufA_h, scale, shift, NC);
    }
    k_final<<<nodeblocks, 256, 0, stream>>>(bufA_h, linW, linB, out);
}

// Round 19
// 547.055 us; speedup vs baseline: 1.1652x; 1.0647x over previous
//
#include <hip/hip_runtime.h>
#include <math.h>

// Problem constants (match reference)
#define NNODES 50000
#define NEDGES 800000
#define ETOT   (NNODES + NEDGES)   // 850000 edges incl. self-loops
#define EDIM   10
#define SMEPS  1e-16f
#define BNEPS  1e-5f
#define NSLOPE 0.2f

#define EASUMB 256                      // easum partial blocks
#define BNB    256                      // bnstats partial blocks
#define CAP    64                       // padded CSR capacity per node
#define PLACEB ((ETOT + 255) / 256)     // 3321
#define CONCB  12500                    // concat blocks (NNODES*64 units /256)
#define WCVTB  576
// fused prep grid: roles interleaved b%5 (place : concat/wcvt/easum = 1 : 4)
#define PREPQ  3334
#define PREPG  (5 * PREPQ)              // 16670 blocks

typedef _Float16 f16;
typedef f16 f16x8 __attribute__((ext_vector_type(8)));
typedef f16 f16x4 __attribute__((ext_vector_type(4)));
typedef float f32x4 __attribute__((ext_vector_type(4)));

// ---------------------------------------------------------------------------
// Fused preprocessing: CSR place (atomic, latency-bound) runs CONCURRENTLY
// with concat/wcvt/easum (throughput-bound) via interleaved block roles —
// the only concurrency mechanism available under graph capture (no streams).
// place: slot = dst*CAP + atomicAdd(deg[dst]); max degree ~43 << CAP=64;
// overflow list keeps correctness unconditional (cold path).
// ---------------------------------------------------------------------------
__global__ __launch_bounds__(256) void k_prep(
        const int* __restrict__ esrc, const int* __restrict__ edst,
        int* __restrict__ deg, int* __restrict__ csr_src, int* __restrict__ perm,
        int* __restrict__ ovf_cnt, int* __restrict__ ovf_src, int* __restrict__ ovf_dst,
        const float* __restrict__ x, const float* __restrict__ cdk,
        f16* __restrict__ outA,
        const float* __restrict__ W0, const float* __restrict__ W1,
        const float* __restrict__ W2, f16* __restrict__ Wt0,
        f16* __restrict__ Wt1, f16* __restrict__ Wt2,
        const float* __restrict__ ea, float* __restrict__ eapart) {
    __shared__ float sm[256];
    const int b = blockIdx.x, t = threadIdx.x;
    const int r = b % 5, q = b / 5;

    if (r == 0) {
        // ---- role: CSR place ----
        if (q >= PLACEB) return;
        int e = q * 256 + t;
        if (e >= ETOT) return;
        int s, d;
        if (e < NEDGES) { s = esrc[e]; d = edst[e]; }
        else            { s = d = e - NEDGES; }      // self-loop
        int pos = atomicAdd(&deg[d], 1);
        if (pos < CAP) {
            int slot = d * CAP + pos;
            csr_src[slot] = s;
            perm[e] = slot;
        } else {                                     // never in practice
            int k = atomicAdd(ovf_cnt, 1);
            ovf_src[k] = s;
            ovf_dst[k] = d;
            perm[e] = -1 - k;
        }
        return;
    }
    int id = q * 4 + (r - 1);
    if (id < CONCB) {
        // ---- role: concat h0 = [x | cdk | 0-pad] -> fp16 [N,256], x4 vec ----
        int u = id * 256 + t;            // unit = 4 consecutive cols
        int n = u >> 6, g = u & 63;
        f16x4 o;
        if (g < 10) {
            float4 v = *(const float4*)&x[(long)n * 40 + g * 4];
            o[0] = (f16)v.x; o[1] = (f16)v.y; o[2] = (f16)v.z; o[3] = (f16)v.w;
        } else if (g < 60) {
            float4 v = *(const float4*)&cdk[(long)n * 200 + g * 4 - 40];
            o[0] = (f16)v.x; o[1] = (f16)v.y; o[2] = (f16)v.z; o[3] = (f16)v.w;
        } else {
            o[0] = (f16)0.f; o[1] = (f16)0.f; o[2] = (f16)0.f; o[3] = (f16)0.f;
        }
        *(f16x4*)&outA[(long)n * 256 + g * 4] = o;
    } else if (id < CONCB + WCVTB) {
        // ---- role: weight transpose Wt[n][k] = fp16(W[k][n]) ----
        int i = (id - CONCB) * 256 + t;
        const float* W; f16* Wt; int K, NC, j;
        if (i < 65536)       { W = W0; Wt = Wt0; K = 240; NC = 256; j = i; }
        else if (i < 131072) { W = W1; Wt = Wt1; K = 256; NC = 256; j = i - 65536; }
        else if (i < 147456) { W = W2; Wt = Wt2; K = 256; NC = 64;  j = i - 131072; }
        else return;
        int n = j >> 8, k = j & 255;
        Wt[j] = (k < K) ? (f16)W[k * NC + n] : (f16)0.f;
    } else if (id < CONCB + WCVTB + EASUMB) {
        // ---- role: edge_attr column sums -> per-block partials ----
        int lb = id - CONCB - WCVTB;     // 0..255
        float acc[EDIM];
#pragma unroll
        for (int d = 0; d < EDIM; ++d) acc[d] = 0.f;
        const int np = NEDGES / 2;       // row pairs
        for (int p = lb * 256 + t; p < np; p += EASUMB * 256) {
            const float4* qq = (const float4*)&ea[(long)p * 20];
            float4 v0 = qq[0], v1 = qq[1], v2 = qq[2], v3 = qq[3], v4 = qq[4];
            acc[0] += v0.x + v2.z;
            acc[1] += v0.y + v2.w;
            acc[2] += v0.z + v3.x;
            acc[3] += v0.w + v3.y;
            acc[4] += v1.x + v3.z;
            acc[5] += v1.y + v3.w;
            acc[6] += v1.z + v4.x;
            acc[7] += v1.w + v4.y;
            acc[8] += v2.x + v4.z;
            acc[9] += v2.y + v4.w;
        }
        for (int d = 0; d < EDIM; ++d) {
            sm[t] = acc[d];
            __syncthreads();
            for (int s = 128; s > 0; s >>= 1) {
                if (t < s) sm[t] += sm[t + s];
                __syncthreads();
            }
            if (t == 0) eapart[lb * EDIM + d] = sm[0];
            __syncthreads();
        }
    }
}

// ---------------------------------------------------------------------------
// fp16 MFMA GEMM + fused attention-coefficient epilogue.
// ---------------------------------------------------------------------------
#define GM_LDS 40
__global__ __launch_bounds__(256) void k_gemm_h(const f16* __restrict__ A,
                                                const f16* __restrict__ Bt,
                                                f16* __restrict__ C,
                                                const float* __restrict__ a_s,
                                                const float* __restrict__ a_d,
                                                float* __restrict__ als,
                                                float* __restrict__ ald,
                                                int M, int NC, int H) {
    __shared__ f16 As[128 * GM_LDS];
    __shared__ f16 Bs[64 * GM_LDS];
    const int t    = threadIdx.x;
    const int w    = t >> 6;
    const int lane = t & 63;
    const int row0 = blockIdx.x * 128;
    const int col0 = blockIdx.y * 64;

    const int ar = t >> 1;              // A stage: row 0..127
    const int ak = (t & 1) * 16;        //          16-half chunk offset 0/16
    const int bn = t >> 2;              // B stage: n 0..63
    const int bk = (t & 3) * 8;         //          k-offset 0/8/16/24

    const int l16 = lane & 15;
    const int kg  = lane >> 4;

    f32x4 acc[2][4];
#pragma unroll
    for (int i = 0; i < 2; ++i)
#pragma unroll
        for (int j = 0; j < 4; ++j) acc[i][j] = {0.f, 0.f, 0.f, 0.f};

    for (int k0 = 0; k0 < 256; k0 += 32) {
        f16x8 av0, av1;
#pragma unroll
        for (int i = 0; i < 8; ++i) { av0[i] = (f16)0.f; av1[i] = (f16)0.f; }
        if (row0 + ar < M) {
            const f16* ap = &A[(long)(row0 + ar) * 256 + k0 + ak];
            av0 = *(const f16x8*)ap;
            av1 = *(const f16x8*)(ap + 8);
        }
        *(f16x8*)&As[ar * GM_LDS + ak]     = av0;
        *(f16x8*)&As[ar * GM_LDS + ak + 8] = av1;
        f16x8 bv = *(const f16x8*)&Bt[(long)(col0 + bn) * 256 + k0 + bk];
        *(f16x8*)&Bs[bn * GM_LDS + bk] = bv;
        __syncthreads();

        f16x8 afr[2], bfr[4];
#pragma unroll
        for (int mi = 0; mi < 2; ++mi)
            afr[mi] = *(const f16x8*)&As[(w * 32 + mi * 16 + l16) * GM_LDS + kg * 8];
#pragma unroll
        for (int ni = 0; ni < 4; ++ni)
            bfr[ni] = *(const f16x8*)&Bs[(ni * 16 + l16) * GM_LDS + kg * 8];
#pragma unroll
        for (int mi = 0; mi < 2; ++mi)
#pragma unroll
            for (int ni = 0; ni < 4; ++ni)
                acc[mi][ni] = __builtin_amdgcn_mfma_f32_16x16x32_f16(
                    afr[mi], bfr[ni], acc[mi][ni], 0, 0, 0);
        __syncthreads();
    }

    // C write
#pragma unroll
    for (int mi = 0; mi < 2; ++mi)
#pragma unroll
        for (int ni = 0; ni < 4; ++ni)
#pragma unroll
            for (int j = 0; j < 4; ++j) {
                int r = row0 + w * 32 + mi * 16 + kg * 4 + j;
                if (r < M) C[(long)r * NC + col0 + ni * 16 + l16] = (f16)acc[mi][ni][j];
            }

    // fused al_s/al_d: this block's 64 cols = head hidx fully
    const int hidx = blockIdx.y;
    float asv[4], adv[4];
#pragma unroll
    for (int ni = 0; ni < 4; ++ni) {
        asv[ni] = a_s[hidx * 64 + ni * 16 + l16];
        adv[ni] = a_d[hidx * 64 + ni * 16 + l16];
    }
#pragma unroll
    for (int mi = 0; mi < 2; ++mi)
#pragma unroll
        for (int j = 0; j < 4; ++j) {
            float ps = acc[mi][0][j] * asv[0] + acc[mi][1][j] * asv[1]
                     + acc[mi][2][j] * asv[2] + acc[mi][3][j] * asv[3];
            float pd = acc[mi][0][j] * adv[0] + acc[mi][1][j] * adv[1]
                     + acc[mi][2][j] * adv[2] + acc[mi][3][j] * adv[3];
#pragma unroll
            for (int o = 1; o < 16; o <<= 1) {
                ps += __shfl_xor(ps, o);
                pd += __shfl_xor(pd, o);
            }
            int r = row0 + w * 32 + mi * 16 + kg * 4 + j;
            if (l16 == 0 && r < M) {
                als[(long)r * H + hidx] = ps;
                ald[(long)r * H + hidx] = pd;
            }
        }
}

// All 3 layers' Ve[d,h] and loop_al[h] in one launch (block = layer, 1 wave).
__global__ void k_ve_all(const float* __restrict__ We0, const float* __restrict__ ae0,
                         const float* __restrict__ We1, const float* __restrict__ ae1,
                         const float* __restrict__ We2, const float* __restrict__ ae2,
                         const float* __restrict__ eapart,
                         float* __restrict__ VeAll, float* __restrict__ laAll) {
    int l = blockIdx.x;
    const float* We = (l == 0) ? We0 : (l == 1) ? We1 : We2;
    const float* ae = (l == 0) ? ae0 : (l == 1) ? ae1 : ae2;
    int H = (l == 2) ? 1 : 4;
    float* Ve = VeAll + l * 48;
    float* la = laAll + l * 4;
    int t = threadIdx.x;          // 0..63, one wave

    float ac[EDIM];
#pragma unroll
    for (int d = 0; d < EDIM; ++d) ac[d] = 0.f;
    for (int r = t; r < EASUMB; r += 64) {
#pragma unroll
        for (int d = 0; d < EDIM; ++d) ac[d] += eapart[r * EDIM + d];
    }
#pragma unroll
    for (int o = 1; o < 64; o <<= 1) {
#pragma unroll
        for (int d = 0; d < EDIM; ++d) ac[d] += __shfl_xor(ac[d], o);
    }

    if (t < EDIM * H) {
        int d = t / H, h = t % H;
        float s = 0.f;
        for (int c = 0; c < 64; ++c) s += We[d * (H * 64) + h * 64 + c] * ae[h * 64 + c];
        Ve[d * H + h] = s;
    }
    __syncthreads();
    if (t < H) {
        float s = 0.f;
        for (int d = 0; d < EDIM; ++d) s += (ac[d] * (1.0f / NEDGES)) * Ve[d * H + t];
        la[t] = s;
    }
}

// Edge-parallel alpha (fp16 logits), written at padded slot via perm.
// Negative perm -> overflow entry (cold path).
template <int H>
__global__ void k_edge(const float* __restrict__ ea, const int* __restrict__ esrc,
                       const int* __restrict__ edst, const float* __restrict__ als,
                       const float* __restrict__ ald, const float* __restrict__ Ve,
                       const float* __restrict__ loop_al, const int* __restrict__ perm,
                       f16* __restrict__ alpha, f16* __restrict__ alpha_ovf) {
    int e = blockIdx.x * blockDim.x + threadIdx.x;
    if (e >= ETOT) return;
    int s, d;
    float ale[H];
    if (e < NEDGES) {
        s = esrc[e]; d = edst[e];
#pragma unroll
        for (int h = 0; h < H; ++h) ale[h] = 0.f;
#pragma unroll
        for (int dd = 0; dd < EDIM; ++dd) {
            float v = ea[(long)e * EDIM + dd];
#pragma unroll
            for (int h = 0; h < H; ++h) ale[h] = fmaf(v, Ve[dd * H + h], ale[h]);
        }
    } else {
        s = d = e - NEDGES;
#pragma unroll
        for (int h = 0; h < H; ++h) ale[h] = loop_al[h];
    }
    int slot = perm[e];
    f16* dst = (slot >= 0) ? &alpha[(long)slot * H]
                           : &alpha_ovf[(long)(-1 - slot) * H];
#pragma unroll
    for (int h = 0; h < H; ++h) {
        float a = als[s * H + h] + ald[d * H + h] + ale[h];
        a = (a > 0.f) ? a : NSLOPE * a;
        dst[h] = (f16)a;
    }
}

// ---------------------------------------------------------------------------
// Node-parallel softmax + aggregation on the PADDED CSR (o0 = gw*CAP,
// cnt = min(deg,CAP)). Overflow entries (deg>CAP, never in practice) are
// folded in after the wave reductions. 4-deep MLP gather (measured optimum).
// ---------------------------------------------------------------------------
template <int H>
__global__ __launch_bounds__(256) void k_agg(const f16* __restrict__ xp,
                                             const f16* __restrict__ alpha,
                                             const int* __restrict__ deg,
                                             const int* __restrict__ csr_src,
                                             const int* __restrict__ ovf_cnt,
                                             const int* __restrict__ ovf_src,
                                             const int* __restrict__ ovf_dst,
                                             const f16* __restrict__ alpha_ovf,
                                             f16* __restrict__ out) {
    int gw   = (blockIdx.x * blockDim.x + threadIdx.x) >> 6;
    int lane = threadIdx.x & 63;
    if (gw >= NNODES) return;
    int dcount = deg[gw];
    int cnt = min(dcount, CAP);
    int o0 = gw * CAP;
    int o1 = o0 + cnt;
    bool ovf = (dcount > CAP);

    if constexpr (H == 4) {
        constexpr int T = 4;                 // covers CAP=64 edges
        int h  = lane >> 4;
        int il = lane & 15;
        int glane = lane & 48;               // first lane of this head's group

        // pass 1: distributed load of alpha + csr_src (register-cached)
        float av[T];
        int   idx[T];
        float mx = -INFINITY;
#pragma unroll
        for (int t = 0; t < T; ++t) {
            int s = o0 + t * 16 + il;
            bool ok = (s < o1);
            float a = ok ? (float)alpha[(long)s * 4 + h] : -INFINITY;
            idx[t] = ok ? csr_src[s] : 0;
            av[t] = a;
            mx = fmaxf(mx, a);
        }
#pragma unroll
        for (int o = 1; o < 16; o <<= 1) mx = fmaxf(mx, __shfl_xor(mx, o));
        if (ovf) {                            // cold path: fold overflow max
            int nov = *ovf_cnt;
            for (int k = 0; k < nov; ++k)
                if (ovf_dst[k] == gw)
                    mx = fmaxf(mx, (float)alpha_ovf[(long)k * 4 + h]);
        }

        // pass 2: exp from registers, group-reduced denominator
        float den = 0.f;
#pragma unroll
        for (int t = 0; t < T; ++t) {
            float e = expf(av[t] - mx);      // exp(-inf)=0 handles padding
            av[t] = e;
            den += e;
        }
#pragma unroll
        for (int o = 1; o < 16; o <<= 1) den += __shfl_xor(den, o);
        if (ovf) {                            // cold path: fold overflow den
            int nov = *ovf_cnt;
            for (int k = 0; k < nov; ++k)
                if (ovf_dst[k] == gw)
                    den += expf((float)alpha_ovf[(long)k * 4 + h] - mx);
        }
        float di = 1.0f / (den + SMEPS);

        // pass 3: weighted gather, 4-way unrolled (4 loads in flight)
        float4 acc0 = make_float4(0.f, 0.f, 0.f, 0.f);
        float4 acc1 = make_float4(0.f, 0.f, 0.f, 0.f);
#pragma unroll
        for (int t = 0; t < T; ++t) {
            int base = t * 16;
            if (base >= cnt) break;
            int c2 = min(16, cnt - base);
            int j = 0;
            for (; j + 4 <= c2; j += 4) {
                float w0 = __shfl(av[t],  glane + j,     64);
                int  sn0 = __shfl(idx[t], glane + j,     64);
                float w1 = __shfl(av[t],  glane + j + 1, 64);
                int  sn1 = __shfl(idx[t], glane + j + 1, 64);
                float w2 = __shfl(av[t],  glane + j + 2, 64);
                int  sn2 = __shfl(idx[t], glane + j + 2, 64);
                float w3 = __shfl(av[t],  glane + j + 3, 64);
                int  sn3 = __shfl(idx[t], glane + j + 3, 64);
                f16x4 x0 = *(const f16x4*)&xp[(long)sn0 * 256 + lane * 4];
                f16x4 x1 = *(const f16x4*)&xp[(long)sn1 * 256 + lane * 4];
                f16x4 x2 = *(const f16x4*)&xp[(long)sn2 * 256 + lane * 4];
                f16x4 x3 = *(const f16x4*)&xp[(long)sn3 * 256 + lane * 4];
                acc0.x = fmaf(w0, (float)x0[0], acc0.x);
                acc0.y = fmaf(w0, (float)x0[1], acc0.y);
                acc0.z = fmaf(w0, (float)x0[2], acc0.z);
                acc0.w = fmaf(w0, (float)x0[3], acc0.w);
                acc1.x = fmaf(w1, (float)x1[0], acc1.x);
                acc1.y = fmaf(w1, (float)x1[1], acc1.y);
                acc1.z = fmaf(w1, (float)x1[2], acc1.z);
                acc1.w = fmaf(w1, (float)x1[3], acc1.w);
                acc0.x = fmaf(w2, (float)x2[0], acc0.x);
                acc0.y = fmaf(w2, (float)x2[1], acc0.y);
                acc0.z = fmaf(w2, (float)x2[2], acc0.z);
                acc0.w = fmaf(w2, (float)x2[3], acc0.w);
                acc1.x = fmaf(w3, (float)x3[0], acc1.x);
                acc1.y = fmaf(w3, (float)x3[1], acc1.y);
                acc1.z = fmaf(w3, (float)x3[2], acc1.z);
                acc1.w = fmaf(w3, (float)x3[3], acc1.w);
            }
            for (; j < c2; ++j) {
                float w  = __shfl(av[t],  glane + j, 64);
                int   sn = __shfl(idx[t], glane + j, 64);
                f16x4 xh = *(const f16x4*)&xp[(long)sn * 256 + lane * 4];
                acc0.x = fmaf(w, (float)xh[0], acc0.x);
                acc0.y = fmaf(w, (float)xh[1], acc0.y);
                acc0.z = fmaf(w, (float)xh[2], acc0.z);
                acc0.w = fmaf(w, (float)xh[3], acc0.w);
            }
        }
        if (ovf) {                            // cold path: fold overflow edges
            int nov = *ovf_cnt;
            for (int k = 0; k < nov; ++k) {
                if (ovf_dst[k] == gw) {
                    float w  = expf((float)alpha_ovf[(long)k * 4 + h] - mx);
                    int   sn = ovf_src[k];
                    f16x4 xh = *(const f16x4*)&xp[(long)sn * 256 + lane * 4];
                    acc0.x = fmaf(w, (float)xh[0], acc0.x);
                    acc0.y = fmaf(w, (float)xh[1], acc0.y);
                    acc0.z = fmaf(w, (float)xh[2], acc0.z);
                    acc0.w = fmaf(w, (float)xh[3], acc0.w);
                }
            }
        }
        f16x4 o4 = {(f16)((acc0.x + acc1.x) * di), (f16)((acc0.y + acc1.y) * di),
                    (f16)((acc0.z + acc1.z) * di), (f16)((acc0.w + acc1.w) * di)};
        *(f16x4*)&out[(long)gw * 256 + lane * 4] = o4;
    } else {
        // H == 1: one lane per column, CAP=64 edges covered in one stripe
        int s = o0 + lane;
        bool ok = (lane < cnt);
        float av0 = ok ? (float)alpha[s] : -INFINITY;
        int   id0 = ok ? csr_src[s] : 0;
        float mx = av0;
#pragma unroll
        for (int o = 1; o < 64; o <<= 1) mx = fmaxf(mx, __shfl_xor(mx, o));
        if (ovf) {
            int nov = *ovf_cnt;
            for (int k = 0; k < nov; ++k)
                if (ovf_dst[k] == gw)
                    mx = fmaxf(mx, (float)alpha_ovf[k]);
        }
        float e0 = expf(av0 - mx);
        float den = e0;
#pragma unroll
        for (int o = 1; o < 64; o <<= 1) den += __shfl_xor(den, o);
        if (ovf) {
            int nov = *ovf_cnt;
            for (int k = 0; k < nov; ++k)
                if (ovf_dst[k] == gw)
                    den += expf((float)alpha_ovf[k] - mx);
        }
        float di = 1.0f / (den + SMEPS);

        float acc0 = 0.f, acc1 = 0.f;
        int j = 0;
        for (; j + 4 <= cnt; j += 4) {
            float w0 = __shfl(e0,  j,     64);
            int  sn0 = __shfl(id0, j,     64);
            float w1 = __shfl(e0,  j + 1, 64);
            int  sn1 = __shfl(id0, j + 1, 64);
            float w2 = __shfl(e0,  j + 2, 64);
            int  sn2 = __shfl(id0, j + 2, 64);
            float w3 = __shfl(e0,  j + 3, 64);
            int  sn3 = __shfl(id0, j + 3, 64);
            float x0 = (float)xp[(long)sn0 * 64 + lane];
            float x1 = (float)xp[(long)sn1 * 64 + lane];
            float x2 = (float)xp[(long)sn2 * 64 + lane];
            float x3 = (float)xp[(long)sn3 * 64 + lane];
            acc0 = fmaf(w0, x0, acc0);
            acc1 = fmaf(w1, x1, acc1);
            acc0 = fmaf(w2, x2, acc0);
            acc1 = fmaf(w3, x3, acc1);
        }
        for (; j < cnt; ++j) {
            float w  = __shfl(e0,  j, 64);
            int   sn = __shfl(id0, j, 64);
            acc0 = fmaf(w, (float)xp[(long)sn * 64 + lane], acc0);
        }
        if (ovf) {
            int nov = *ovf_cnt;
            for (int k = 0; k < nov; ++k) {
                if (ovf_dst[k] == gw) {
                    float w  = expf((float)alpha_ovf[k] - mx);
                    int   sn = ovf_src[k];
                    acc0 = fmaf(w, (float)xp[(long)sn * 64 + lane], acc0);
                }
            }
        }
        out[(long)gw * 64 + lane] = (f16)((acc0 + acc1) * di);
    }
}

// ---------------------------------------------------------------------------
// BatchNorm (eval stats) + ELU — per-block partials, NO float atomics.
// GAT bias b skipped: cancels exactly in (x - mean).
// ---------------------------------------------------------------------------
__global__ void k_bnstats(const f16* __restrict__ x, int width,
                          float* __restrict__ s1p, float* __restrict__ s2p) {
    __shared__ float sa[256], sb[256];
    int col  = threadIdx.x % width;
    int rsub = threadIdx.x / width;
    int rpb  = 256 / width;
    float a = 0.f, b = 0.f;
    for (int r = blockIdx.x * rpb + rsub; r < NNODES; r += gridDim.x * rpb) {
        float v = (float)x[(long)r * width + col];
        a += v; b += v * v;
    }
    if (rpb == 1) {
        s1p[blockIdx.x * width + col] = a;
        s2p[blockIdx.x * width + col] = b;
    } else {
        sa[threadIdx.x] = a;
        sb[threadIdx.x] = b;
        __syncthreads();
        if (rsub == 0) {
            for (int k = 1; k < rpb; ++k) {
                a += sa[col + k * width];
                b += sb[col + k * width];
            }
            s1p[blockIdx.x * width + col] = a;
            s2p[blockIdx.x * width + col] = b;
        }
    }
}

__global__ void k_bnfin(const float* __restrict__ s1p, const float* __restrict__ s2p,
                        const float* __restrict__ g, const float* __restrict__ be,
                        int width, float* __restrict__ scale, float* __restrict__ shift) {
    int c = threadIdx.x;
    if (c >= width) return;
    float s1 = 0.f, s2 = 0.f;
    for (int k = 0; k < BNB; ++k) {          // coalesced: consecutive c per k
        s1 += s1p[k * width + c];
        s2 += s2p[k * width + c];
    }
    float mu  = s1 * (1.0f / NNODES);
    float var = s2 * (1.0f / NNODES) - mu * mu;
    float sc  = g[c] * rsqrtf(var + BNEPS);
    scale[c] = sc;
    shift[c] = be[c] - mu * sc;
}

// BN+ELU; FINAL variant fuses the last linear+sigmoid: 16 consecutive threads
// cover one 64-col row -> shfl-reduce the linW dot, group leader writes out.
template <bool FINAL>
__global__ void k_bnelu_h(const f16* __restrict__ xin, f16* __restrict__ xout,
                          const float* __restrict__ scale, const float* __restrict__ shift,
                          int width, const float* __restrict__ linW,
                          const float* __restrict__ linB, float* __restrict__ out) {
    long i = (long)(blockIdx.x * blockDim.x + threadIdx.x);
    long total = (long)NNODES * width;
    if (i * 4 >= total) return;
    f16x4 v4 = *(const f16x4*)&xin[i * 4];
    int c = (int)((i * 4) % width);      // width % 4 == 0 -> no row crossing
    float4 sc = *(const float4*)&scale[c];
    float4 sh = *(const float4*)&shift[c];
    float y0 = (float)v4[0] * sc.x + sh.x;
    float y1 = (float)v4[1] * sc.y + sh.y;
    float y2 = (float)v4[2] * sc.z + sh.z;
    float y3 = (float)v4[3] * sc.w + sh.w;
    y0 = (y0 > 0.f) ? y0 : expm1f(y0);
    y1 = (y1 > 0.f) ? y1 : expm1f(y1);
    y2 = (y2 > 0.f) ? y2 : expm1f(y2);
    y3 = (y3 > 0.f) ? y3 : expm1f(y3);
    if constexpr (!FINAL) {
        f16x4 o = {(f16)y0, (f16)y1, (f16)y2, (f16)y3};
        *(f16x4*)&xout[i * 4] = o;
    } else {
        // width == 64: 16-thread groups (aligned in-wave) reduce the row dot
        float wsum = y0 * linW[c] + y1 * linW[c + 1]
                   + y2 * linW[c + 2] + y3 * linW[c + 3];
#pragma unroll
        for (int o = 1; o < 16; o <<= 1) wsum += __shfl_xor(wsum, o);
        if ((threadIdx.x & 15) == 0) {
            long row = (i * 4) / width;
            out[row] = 1.0f / (1.0f + expf(-(wsum + linB[0])));
        }
    }
}

// ---------------------------------------------------------------------------
extern "C" void kernel_launch(void* const* d_in, const int* in_sizes, int n_in,
                              void* d_out, int out_size, void* d_ws, size_t ws_size,
                              hipStream_t stream) {
    (void)in_sizes; (void)n_in; (void)out_size; (void)ws_size;
    const float* x    = (const float*)d_in[0];
    const float* cdk  = (const float*)d_in[1];
    const int*   esrc = (const int*)d_in[2];
    const int*   edst = (const int*)d_in[3];
    const float* ea   = (const float*)d_in[4];
    const float* W[3]   = {(const float*)d_in[5],  (const float*)d_in[13], (const float*)d_in[21]};
    const float* as_[3] = {(const float*)d_in[6],  (const float*)d_in[14], (const float*)d_in[22]};
    const float* ad_[3] = {(const float*)d_in[7],  (const float*)d_in[15], (const float*)d_in[23]};
    const float* We_[3] = {(const float*)d_in[8],  (const float*)d_in[16], (const float*)d_in[24]};
    const float* ae_[3] = {(const float*)d_in[9],  (const float*)d_in[17], (const float*)d_in[25]};
    // b{i} (d_in[10/18/26]) skipped: exactly cancels in BatchNorm
    const float* g_[3]  = {(const float*)d_in[11], (const float*)d_in[19], (const float*)d_in[27]};
    const float* be_[3] = {(const float*)d_in[12], (const float*)d_in[20], (const float*)d_in[28]};
    const float* linW = (const float*)d_in[29];
    const float* linB = (const float*)d_in[30];
    float* out = (float*)d_out;

    // workspace layout. Zero region (deg + ovf_cnt) FIRST -> 1 small memset.
    char* base = (char*)d_ws;
    size_t p = 0;
    auto alloc = [&](size_t bytes) -> void* {
        void* r = base + p;
        p = (p + bytes + 255) & ~(size_t)255;
        return r;
    };
    // --- zero region ---
    int*   deg     = (int*)alloc((size_t)NNODES * 4);
    int*   ovf_cnt = (int*)alloc(4);
    size_t zero_bytes = p;
    // --- rest (fully written before read; no zero-init needed) ---
    float* eapart  = (float*)alloc((size_t)EASUMB * EDIM * 4);
    float* s1p     = (float*)alloc((size_t)BNB * 256 * 4);
    float* s2p     = (float*)alloc((size_t)BNB * 256 * 4);
    int*   csr_src = (int*)alloc((size_t)NNODES * CAP * 4);
    int*   perm    = (int*)alloc((size_t)ETOT * 4);
    f16*   alpha   = (f16*)alloc((size_t)NNODES * CAP * 4 * 2);
    int*   ovf_src = (int*)alloc((size_t)ETOT * 4);
    int*   ovf_dst = (int*)alloc((size_t)ETOT * 4);
    f16*   alpha_o = (f16*)alloc((size_t)ETOT * 4 * 2);
    float* als     = (float*)alloc((size_t)NNODES * 4 * 4);
    float* ald     = (float*)alloc((size_t)NNODES * 4 * 4);
    float* VeAll   = (float*)alloc((size_t)3 * 48 * 4);
    float* laAll   = (float*)alloc((size_t)3 * 4 * 4);
    float* scale   = (float*)alloc(256 * 4);
    float* shift   = (float*)alloc(256 * 4);
    f16*   Wt[3];
    Wt[0]          = (f16*)alloc((size_t)256 * 256 * 2);
    Wt[1]          = (f16*)alloc((size_t)256 * 256 * 2);
    Wt[2]          = (f16*)alloc((size_t)64 * 256 * 2);
    f16*   bufA_h  = (f16*)alloc((size_t)NNODES * 256 * 2);   // GEMM A input
    f16*   bufXp_h = (f16*)alloc((size_t)NNODES * 256 * 2);   // GEMM output (xp)
    f16*   bufC_h  = (f16*)alloc((size_t)NNODES * 256 * 2);   // agg output (fp16)

    hipMemsetAsync(base, 0, zero_bytes, stream);

    int eb = (ETOT + 255) / 256;
    // fused prep: place || concat || wcvt || easum (interleaved block roles)
    k_prep<<<PREPG, 256, 0, stream>>>(esrc, edst, deg, csr_src, perm,
                                      ovf_cnt, ovf_src, ovf_dst,
                                      x, cdk, bufA_h,
                                      W[0], W[1], W[2], Wt[0], Wt[1], Wt[2],
                                      ea, eapart);
    k_ve_all<<<3, 64, 0, stream>>>(We_[0], ae_[0], We_[1], ae_[1], We_[2], ae_[2],
                                   eapart, VeAll, laAll);

    const int nodeblocks = (NNODES * 64) / 256;   // wave per node, 4 waves/block
    const int mblocks = (NNODES + 127) / 128;     // 391

    for (int l = 0; l < 3; ++l) {
        const int H  = (l == 2) ? 1 : 4;
        const int NC = H * 64;
        const float* Ve  = VeAll + l * 48;
        const float* la  = laAll + l * 4;
        dim3 gg(mblocks, NC / 64);
        k_gemm_h<<<gg, 256, 0, stream>>>(bufA_h, Wt[l], bufXp_h,
                                         as_[l], ad_[l], als, ald, NNODES, NC, H);
        if (H == 4) {
            k_edge<4><<<eb, 256, 0, stream>>>(ea, esrc, edst, als, ald, Ve, la,
                                              perm, alpha, alpha_o);
            k_agg<4><<<nodeblocks, 256, 0, stream>>>(bufXp_h, alpha, deg, csr_src,
                                                     ovf_cnt, ovf_src, ovf_dst,
                                                     alpha_o, bufC_h);
        } else {
            k_edge<1><<<eb, 256, 0, stream>>>(ea, esrc, edst, als, ald, Ve, la,
                                              perm, alpha, alpha_o);
            k_agg<1><<<nodeblocks, 256, 0, stream>>>(bufXp_h, alpha, deg, csr_src,
                                                     ovf_cnt, ovf_src, ovf_dst,
                                                     alpha_o, bufC_h);
        }
        k_bnstats<<<BNB, 256, 0, stream>>>(bufC_h, NC, s1p, s2p);
        k_bnfin<<<1, 256, 0, stream>>>(s1p, s2p, g_[l], be_[l], NC, scale, shift);
        if (l < 2) {
            k_bnelu_h<false><<<(NNODES * NC / 4 + 255) / 256, 256, 0, stream>>>(
                bufC_h, bufA_h, scale, shift, NC, nullptr, nullptr, nullptr);
        } else {
            k_bnelu_h<true><<<(NNODES * 64 / 4 + 255) / 256, 256, 0, stream>>>(
                bufC_h, nullptr, scale, shift, 64, linW, linB, out);
        }
    }
}